// Round 1
// baseline (408.377 us; speedup 1.0000x reference)
//
#include <hip/hip_runtime.h>
#include <math.h>

#define N 4096
#define BATCH 32
#define KT 256

static __device__ __forceinline__ float fast_exp2(float x) {
#if __has_builtin(__builtin_amdgcn_exp2f)
  return __builtin_amdgcn_exp2f(x);
#else
  return exp2f(x);
#endif
}

// async global->LDS, 16B per lane: lane i writes lds_base + i*16 (wave-uniform base!)
#if __has_builtin(__builtin_amdgcn_global_load_lds)
#define HAVE_ASYNC_LDS 1
static __device__ __forceinline__ void async_cp16(const float* g, float* lds_base) {
  __builtin_amdgcn_global_load_lds(
      (const __attribute__((address_space(1))) void*)g,
      (__attribute__((address_space(3))) void*)lds_base, 16, 0, 0);
}
#else
#define HAVE_ASYNC_LDS 0
#endif

// R5: single-buffered X tile. Double-buffering cost 64 KB LDS -> <=2 blocks/CU
// and the per-tile vmcnt(0) barrier drain had nothing to overlap with
// (VALUBusy 31%, HBM 12.6%). 33.8 KB -> 4 blocks/CU by LDS; 140 VGPR -> 3
// waves/SIMD -> 3 resident blocks whose staggered phases cover each other's
// stage-wait. Intra-block overlap is deliberately sacrificed for TLP.
union GemmSmem {
  float xs[BATCH][KT];      // 32 KB: single-buffered X k-tile
  float red[4][64][33];     // 33.8 KB cross-lane reduction (stride 33: conflict-free)
};

// Y[b,i] = sum_{k in [kbeg,kend)} X[b,k]*W[i,k] (+ bias[i] unless PARTIAL).
// 4 waves/block, RPW_ rows/wave; lanes split K (4 k each): W streams straight
// from global to registers (each W element read by exactly one thread), X is
// staged in LDS via async global_load_lds. W for tile kt+1 is prefetched into
// registers before computing kt (hidden under compute; the post-compute barrier
// drain lands after it completes). RPW_=4 -> 1 B LDS per FMA (pipe-balanced).
// REGISTER DISCIPLINE (hard-won over R2/R4):
//  - acc/wc/wn arrays only ever indexed by constants (full unrolls) -> no scratch
//  - RPW=4 body: amdgpu_waves_per_eu(1) -> VGPR cap 512, ~140 regs allocate
//    cleanly (launch_bounds 2nd arg of 2 empirically capped at 128 -> spill)
//  - RPW=2 body: launch_bounds(256,2) caps at 128 VGPR (fits ~100) -> 4 waves/SIMD
template <int RPW_, bool PARTIAL>
__device__ __forceinline__ void gemm_body(const float* __restrict__ X,
    const float* __restrict__ W, const float* __restrict__ bias,
    float* __restrict__ Y, int kbeg, int kend)
{
  __shared__ __align__(16) GemmSmem sm;
  const int t = threadIdx.x;
  const int w = t >> 6;   // wave 0..3
  const int l = t & 63;   // lane
  const int i0 = blockIdx.x * (RPW_ * 4);

  const float* wr[RPW_];
  #pragma unroll
  for (int r = 0; r < RPW_; ++r) wr[r] = &W[(size_t)(i0 + w * RPW_ + r) * N];

  float acc[RPW_][BATCH];
  #pragma unroll
  for (int r = 0; r < RPW_; ++r)
    #pragma unroll
    for (int b = 0; b < BATCH; ++b) acc[r][b] = 0.f;

  // stage X[:, kt0:kt0+KT]: wave w stages rows w*8..w*8+7 (1 KB each)
  auto stage = [&](int kt0) {
    #pragma unroll
    for (int p = 0; p < 8; ++p) {
      int row = w * 8 + p;
#if HAVE_ASYNC_LDS
      async_cp16(&X[(size_t)row * N + kt0 + 4 * l], &sm.xs[row][0]);
#else
      *(float4*)&sm.xs[row][4 * l] = *(const float4*)&X[(size_t)row * N + kt0 + 4 * l];
#endif
    }
  };

  auto compute = [&](float4 (&wc)[RPW_]) {
    #pragma unroll
    for (int b = 0; b < BATCH; ++b) {
      float4 x4 = *(const float4*)&sm.xs[b][4 * l];   // b128, 2-way alias = free
      #pragma unroll
      for (int r = 0; r < RPW_; ++r) {
        acc[r][b] = fmaf(wc[r].x, x4.x, acc[r][b]);
        acc[r][b] = fmaf(wc[r].y, x4.y, acc[r][b]);
        acc[r][b] = fmaf(wc[r].z, x4.z, acc[r][b]);
        acc[r][b] = fmaf(wc[r].w, x4.w, acc[r][b]);
      }
    }
  };

  // prologue: stage tile kbeg, load W tile kbeg
  stage(kbeg);
  float4 wc[RPW_], wn[RPW_];
  #pragma unroll
  for (int r = 0; r < RPW_; ++r) wc[r] = *(const float4*)&wr[r][kbeg + 4 * l];
  __syncthreads();   // drains vmcnt: staging + W loads complete

  #pragma unroll 1
  for (int kt = kbeg + KT; kt < kend; kt += KT) {
    // W for THIS tile's successor: issued before compute -> lands during it
    #pragma unroll
    for (int r = 0; r < RPW_; ++r) wn[r] = *(const float4*)&wr[r][kt + 4 * l];
    compute(wc);
    __syncthreads();  // all waves done reading xs -> buffer reusable (also drains wn, long landed)
    stage(kt);        // re-stage single buffer
    __syncthreads();  // staging visible
    #pragma unroll
    for (int r = 0; r < RPW_; ++r) wc[r] = wn[r];
  }
  compute(wc);
  __syncthreads();    // xs/red union: all LDS reads done before red writes

  // cross-lane (64-lane) reduction; r fully unrolled so acc index is constant
  #pragma unroll
  for (int r = 0; r < RPW_; ++r) {
    #pragma unroll
    for (int b = 0; b < BATCH; ++b) sm.red[w][l][b] = acc[r][b];  // banks (l+b)%32
    __syncthreads();
    if (t < 128) {
      int rw = t >> 5, b = t & 31;
      float s = 0.f;
      #pragma unroll 8
      for (int l2 = 0; l2 < 64; ++l2) s += sm.red[rw][l2][b];
      int i = i0 + rw * RPW_ + r;
      float y = PARTIAL ? s : (s + bias[i]);
      Y[(size_t)b * N + i] = y;
    }
    __syncthreads();
  }
}

__global__ __launch_bounds__(256) __attribute__((amdgpu_waves_per_eu(1)))
void gemm3(const float* __restrict__ X,
           const float* __restrict__ W0, const float* __restrict__ b0, float* __restrict__ Y0,
           const float* __restrict__ W1, const float* __restrict__ b1, float* __restrict__ Y1,
           const float* __restrict__ W2, const float* __restrict__ b2, float* __restrict__ Y2)
{
  const float* W = W0; const float* bias = b0; float* Y = Y0;
  if (blockIdx.y == 1) { W = W1; bias = b1; Y = Y1; }
  else if (blockIdx.y == 2) { W = W2; bias = b2; Y = Y2; }
  gemm_body<4, false>(X, W, bias, Y, 0, N);
}

// R5: Wp GEMM k-split into 2 slabs (grid 1024 = exactly 4 blocks/CU at 33.8 KB
// LDS + <=128 VGPR) writing partials into the dead q/kk workspace buffers.
// Bias + residual + silu moved to finalize_kernel.
__global__ __launch_bounds__(256, 2)
void gemm_p(const float* __restrict__ X, const float* __restrict__ W,
            float* __restrict__ T0, float* __restrict__ T1)
{
  float* T = (blockIdx.y == 0) ? T0 : T1;
  const int kbeg = blockIdx.y * (N / 2);
  gemm_body<2, true>(X, W, nullptr, T, kbeg, kbeg + N / 2);
}

// out = silu(h + (T0 + T1) + bp)   [T0+T1 = h @ Wp.T]
__global__ __launch_bounds__(256)
void finalize_kernel(const float* __restrict__ h, const float* __restrict__ T0,
                     const float* __restrict__ T1, const float* __restrict__ bp,
                     float* __restrict__ out)
{
  int idx = (blockIdx.x * 256 + threadIdx.x) * 4;
  int i = idx & (N - 1);
  float4 hv = *(const float4*)&h[idx];
  float4 a  = *(const float4*)&T0[idx];
  float4 b  = *(const float4*)&T1[idx];
  float4 bb = *(const float4*)&bp[i];
  float4 z, o;
  z.x = hv.x + a.x + b.x + bb.x;
  z.y = hv.y + a.y + b.y + bb.y;
  z.z = hv.z + a.z + b.z + bb.z;
  z.w = hv.w + a.w + b.w + bb.w;
  o.x = z.x / (1.f + fast_exp2(-1.44269504f * z.x));
  o.y = z.y / (1.f + fast_exp2(-1.44269504f * z.y));
  o.z = z.z / (1.f + fast_exp2(-1.44269504f * z.z));
  o.w = z.w / (1.f + fast_exp2(-1.44269504f * z.w));
  *(float4*)&out[idx] = o;
}

// attention: block = (batch b, 256 i's), 1024 threads. Thread (i_loc = t&255,
// jw = t>>8) accumulates s,a over its j-quarter (1024 j); LDS-reduce 4 partials.
// 16 waves/block, 2 blocks/CU -> 32 waves/CU (max occupancy) hides LDS latency.
// No max-subtraction: |q*k| <= ~36 << 88, scale cancels in a/s.
__global__ __launch_bounds__(1024, 2)
void attn_kernel(const float* __restrict__ q, const float* __restrict__ k,
                 const float* __restrict__ v, const float* __restrict__ X,
                 float* __restrict__ h)
{
  __shared__ __align__(16) float ks[N];        // 16 KB
  __shared__ __align__(16) float vs[N];        // 16 KB
  __shared__ float red_s[4][256];              // 4 KB
  __shared__ float red_a[4][256];              // 4 KB
  const int t = threadIdx.x;
  const int wv = t >> 6;    // wave 0..15
  const int ln = t & 63;
  const int b = blockIdx.x >> 4;
  const int chunk = blockIdx.x & 15;

  // stage k,v: wave wv stages 1 KB segment wv of each
#if HAVE_ASYNC_LDS
  async_cp16(&k[(size_t)b * N + wv * 256 + 4 * ln], &ks[wv * 256]);
  async_cp16(&v[(size_t)b * N + wv * 256 + 4 * ln], &vs[wv * 256]);
#else
  *(float4*)&ks[wv * 256 + 4 * ln] = *(const float4*)&k[(size_t)b * N + wv * 256 + 4 * ln];
  *(float4*)&vs[wv * 256 + 4 * ln] = *(const float4*)&v[(size_t)b * N + wv * 256 + 4 * ln];
#endif

  const int i_loc = t & 255;
  const int jw = t >> 8;
  const int i = chunk * 256 + i_loc;
  const float qe = q[(size_t)b * N + i] * 1.44269504f;   // exp(x) = 2^(x*log2e)
  __syncthreads();   // staging complete

  const int j0 = jw * 1024;
  float s0 = 0, s1 = 0, s2 = 0, s3 = 0, a0 = 0, a1 = 0, a2 = 0, a3 = 0;
  #pragma unroll 4
  for (int j = j0; j < j0 + 1024; j += 8) {
    float4 ka = *(const float4*)&ks[j];       // broadcast (all lanes same addr)
    float4 va = *(const float4*)&vs[j];
    float4 kb = *(const float4*)&ks[j + 4];
    float4 vb = *(const float4*)&vs[j + 4];
    float e0 = fast_exp2(qe * ka.x);
    float e1 = fast_exp2(qe * ka.y);
    float e2 = fast_exp2(qe * ka.z);
    float e3 = fast_exp2(qe * ka.w);
    float e4 = fast_exp2(qe * kb.x);
    float e5 = fast_exp2(qe * kb.y);
    float e6 = fast_exp2(qe * kb.z);
    float e7 = fast_exp2(qe * kb.w);
    s0 += e0; a0 = fmaf(e0, va.x, a0);
    s1 += e1; a1 = fmaf(e1, va.y, a1);
    s2 += e2; a2 = fmaf(e2, va.z, a2);
    s3 += e3; a3 = fmaf(e3, va.w, a3);
    s0 += e4; a0 = fmaf(e4, vb.x, a0);
    s1 += e5; a1 = fmaf(e5, vb.y, a1);
    s2 += e6; a2 = fmaf(e6, vb.z, a2);
    s3 += e7; a3 = fmaf(e7, vb.w, a3);
  }
  red_s[jw][i_loc] = (s0 + s1) + (s2 + s3);
  red_a[jw][i_loc] = (a0 + a1) + (a2 + a3);
  __syncthreads();

  if (t < 256) {
    float s = ((red_s[0][t] + red_s[1][t]) + (red_s[2][t] + red_s[3][t]));
    float a = ((red_a[0][t] + red_a[1][t]) + (red_a[2][t] + red_a[3][t]));
    int ii = chunk * 256 + t;
    float att = a / s;
    float z = X[(size_t)b * N + ii] + att;
    h[(size_t)b * N + ii] = z / (1.f + fast_exp2(-1.44269504f * z));  // silu
  }
}

extern "C" void kernel_launch(void* const* d_in, const int* in_sizes, int n_in,
                              void* d_out, int out_size, void* d_ws, size_t ws_size,
                              hipStream_t stream)
{
  const float* x  = (const float*)d_in[0];
  const float* Wq = (const float*)d_in[1];
  const float* bq = (const float*)d_in[2];
  const float* Wk = (const float*)d_in[3];
  const float* bk = (const float*)d_in[4];
  const float* Wv = (const float*)d_in[5];
  const float* bv = (const float*)d_in[6];
  const float* Wp = (const float*)d_in[7];
  const float* bp = (const float*)d_in[8];
  float* out = (float*)d_out;

  float* q  = (float*)d_ws;          // [32][4096]
  float* kk = q  + BATCH * N;
  float* vv = kk + BATCH * N;
  float* h  = vv + BATCH * N;        // total 2 MB

  dim3 g1(N / 16, 3);
  gemm3<<<g1, 256, 0, stream>>>(x, Wq, bq, q, Wk, bk, kk, Wv, bv, vv);
  attn_kernel<<<dim3(BATCH * 16), 1024, 0, stream>>>(q, kk, vv, x, h);
  // q/kk are dead after attn -> reuse as partial buffers for the Wp GEMM
  gemm_p<<<dim3(N / 8, 2), 256, 0, stream>>>(h, Wp, q, kk);
  finalize_kernel<<<dim3(BATCH * N / 1024), 256, 0, stream>>>(h, q, kk, bp, out);
}

// Round 2
// 356.923 us; speedup vs baseline: 1.1442x; 1.1442x over previous
//
#include <hip/hip_runtime.h>
#include <math.h>

#define N 4096
#define BATCH 32

typedef short bf16x8 __attribute__((ext_vector_type(8)));
typedef float f32x4  __attribute__((ext_vector_type(4)));

static __device__ __forceinline__ float fast_exp2(float x) {
#if __has_builtin(__builtin_amdgcn_exp2f)
  return __builtin_amdgcn_exp2f(x);
#else
  return exp2f(x);
#endif
}

// bf16 split helpers (RNE). hi+lo with all 4 MFMA cross terms gives ~2^-17
// relative representation error -> fp32-comparable GEMM accuracy.
static __device__ __forceinline__ unsigned short f2bf(float f) {
  unsigned int u = __float_as_uint(f);
  return (unsigned short)((u + 0x7FFFu + ((u >> 16) & 1u)) >> 16);
}
static __device__ __forceinline__ float bf2f(unsigned short h) {
  return __uint_as_float((unsigned int)h << 16);
}

// async global->LDS (attn staging only)
#if __has_builtin(__builtin_amdgcn_global_load_lds)
#define HAVE_ASYNC_LDS 1
static __device__ __forceinline__ void async_cp16(const float* g, float* lds_base) {
  __builtin_amdgcn_global_load_lds(
      (const __attribute__((address_space(1))) void*)g,
      (__attribute__((address_space(3))) void*)lds_base, 16, 0, 0);
}
#else
#define HAVE_ASYNC_LDS 0
#endif

// ---------------------------------------------------------------------------
// R6: GEMMs moved to MFMA (split-bf16). fp32-VALU floor for the 4 GEMMs was
// ~110us; HBM floor is ~41us. MFMA makes them pure W-streams.
//
// Fragment-order prep: src [32][4096] f32 -> dst = 4 arrays [128 kstep][64 lane][8]
// bf16 (as short):   narr 0: hi b=0..15 | 1: hi b=16..31 | 2: lo b=0..15 | 3: lo b=16..31
// Element (narr,T,l,j) = cvt(src[b = (l&15)|((narr&1)<<4)][k = T*32 + (l>>4)*8 + j]).
// This is exactly the B-fragment layout of mfma_f32_16x16x32_bf16 (B: col=l&15,
// k=(l>>4)*8+j — m92/m97-refchecked), so the GEMM's B loads are single coalesced
// dwordx4 per wave per fragment, L2-resident (512 KB total). No LDS staging.
// ---------------------------------------------------------------------------
__global__ __launch_bounds__(256)
void prep_frags(const float* __restrict__ src, short* __restrict__ dst)
{
  int id = blockIdx.x * 256 + threadIdx.x;   // 0..32767 (grid 128)
  int narr = id >> 13;                       // uniform per block (32 blocks/array)
  int rem  = id & 8191;
  int T = rem >> 6;
  int l = rem & 63;
  int b = (l & 15) | ((narr & 1) << 4);
  int k = T * 32 + ((l >> 4) << 3);
  const float* s = &src[(size_t)b * N + k];
  bf16x8 o;
  #pragma unroll
  for (int j = 0; j < 8; ++j) {
    float f = s[j];
    unsigned short h = f2bf(f);
    if (narr >> 1) h = f2bf(f - bf2f(h));    // lo = bf16(residual)
    o[j] = (short)h;
  }
  *(bf16x8*)&dst[(size_t)id * 8] = o;        // fully coalesced 16B stores
}

// Y[b,i] = sum_k W[i,k] X[b,k] + bias[i]   (SILU: y = silu(resid + y))
// Block = 16 i-rows (i0 = blockIdx.x*16), 4 waves k-split (wave w: k in
// [w*1024,(w+1)*1024)). Per k-step (32 k): lane l loads W[i0+(l&15)][...+(l>>4)*8]
// (8 f32 = 32B; every W byte consumed exactly once -> pure HBM stream), converts
// to hi/lo bf16 in regs (~1.5us/GEMM of VALU, negligible), loads 4 B-frags from
// the frag arrays (coalesced, L2), and issues 8 MFMA (hh,hl,lh,ll x 2 b-halves).
// NO barriers / LDS in the K-loop -> compiler pipelines freely, latency hidden
// by unroll-4 (8 KB W in flight per wave) + 3 blocks/CU TLP.
// Epilogue: 8 KB LDS cross-wave reduce (only syncs in the kernel).
// C/D layout (m89): col = l&15 (batch), row = (l>>4)*4 + reg (i offset).
template <bool SILU>
__device__ __forceinline__ void gemm_mfma_body(
    const float* __restrict__ W, const short* __restrict__ Xf,
    const float* __restrict__ bias, const float* __restrict__ resid,
    float* __restrict__ Y)
{
  const int t = threadIdx.x;
  const int w = t >> 6;              // wave = k-slice
  const int l = t & 63;
  const int i0 = blockIdx.x * 16;

  // A source: row i0+(l&15), k = w*1024 + s*32 + (l>>4)*8
  const float* wrow = &W[(size_t)(i0 + (l & 15)) * N + w * 1024 + ((l >> 4) << 3)];
  // B frags: shorts; narr stride 65536, T stride 512, lane stride 8
  const short* bbase = Xf + w * 16384 + l * 8;

  f32x4 acc0 = {0.f, 0.f, 0.f, 0.f};
  f32x4 acc1 = {0.f, 0.f, 0.f, 0.f};

  #pragma unroll 4
  for (int s = 0; s < 32; ++s) {
    float4 wa = *(const float4*)(wrow + s * 32);
    float4 wb = *(const float4*)(wrow + s * 32 + 4);
    bf16x8 bh0 = *(const bf16x8*)(bbase +     0 + s * 512);
    bf16x8 bh1 = *(const bf16x8*)(bbase + 65536 + s * 512);
    bf16x8 bl0 = *(const bf16x8*)(bbase + 131072 + s * 512);
    bf16x8 bl1 = *(const bf16x8*)(bbase + 196608 + s * 512);

    float wf0 = wa.x, wf1 = wa.y, wf2 = wa.z, wf3 = wa.w;
    float wf4 = wb.x, wf5 = wb.y, wf6 = wb.z, wf7 = wb.w;
    bf16x8 ah, al;
    {
      unsigned short h;
      h = f2bf(wf0); ah[0] = (short)h; al[0] = (short)f2bf(wf0 - bf2f(h));
      h = f2bf(wf1); ah[1] = (short)h; al[1] = (short)f2bf(wf1 - bf2f(h));
      h = f2bf(wf2); ah[2] = (short)h; al[2] = (short)f2bf(wf2 - bf2f(h));
      h = f2bf(wf3); ah[3] = (short)h; al[3] = (short)f2bf(wf3 - bf2f(h));
      h = f2bf(wf4); ah[4] = (short)h; al[4] = (short)f2bf(wf4 - bf2f(h));
      h = f2bf(wf5); ah[5] = (short)h; al[5] = (short)f2bf(wf5 - bf2f(h));
      h = f2bf(wf6); ah[6] = (short)h; al[6] = (short)f2bf(wf6 - bf2f(h));
      h = f2bf(wf7); ah[7] = (short)h; al[7] = (short)f2bf(wf7 - bf2f(h));
    }
    acc0 = __builtin_amdgcn_mfma_f32_16x16x32_bf16(ah, bh0, acc0, 0, 0, 0);
    acc1 = __builtin_amdgcn_mfma_f32_16x16x32_bf16(ah, bh1, acc1, 0, 0, 0);
    acc0 = __builtin_amdgcn_mfma_f32_16x16x32_bf16(ah, bl0, acc0, 0, 0, 0);
    acc1 = __builtin_amdgcn_mfma_f32_16x16x32_bf16(ah, bl1, acc1, 0, 0, 0);
    acc0 = __builtin_amdgcn_mfma_f32_16x16x32_bf16(al, bh0, acc0, 0, 0, 0);
    acc1 = __builtin_amdgcn_mfma_f32_16x16x32_bf16(al, bh1, acc1, 0, 0, 0);
    acc0 = __builtin_amdgcn_mfma_f32_16x16x32_bf16(al, bl0, acc0, 0, 0, 0);
    acc1 = __builtin_amdgcn_mfma_f32_16x16x32_bf16(al, bl1, acc1, 0, 0, 0);
  }

  // cross-wave k-reduction: red[w][n][r][l] (lane-stride 4B -> conflict-free)
  __shared__ float red[4][2][4][64];   // 8 KB
  #pragma unroll
  for (int r = 0; r < 4; ++r) { red[w][0][r][l] = acc0[r]; red[w][1][r][l] = acc1[r]; }
  __syncthreads();

  #pragma unroll
  for (int e = t; e < 512; e += 256) {
    int b  = e >> 4;               // 0..31
    int il = e & 15;               // i - i0
    int n  = b >> 4;
    int lw = (b & 15) | ((il >> 2) << 4);
    int r  = il & 3;
    float v = ((red[0][n][r][lw] + red[1][n][r][lw]) +
               (red[2][n][r][lw] + red[3][n][r][lw]));
    int i = i0 + il;
    float y = v + bias[i];
    if (SILU) {
      float z = resid[(size_t)b * N + i] + y;
      y = z / (1.f + fast_exp2(-1.44269504f * z));
    }
    Y[(size_t)b * N + i] = y;      // 16 consecutive i per 16 threads: 64B segments
  }
}

__global__ __launch_bounds__(256, 3)
void gemm3(const short* __restrict__ Xf,
           const float* __restrict__ W0, const float* __restrict__ b0, float* __restrict__ Y0,
           const float* __restrict__ W1, const float* __restrict__ b1, float* __restrict__ Y1,
           const float* __restrict__ W2, const float* __restrict__ b2, float* __restrict__ Y2)
{
  const float* W = W0; const float* bias = b0; float* Y = Y0;
  if (blockIdx.y == 1) { W = W1; bias = b1; Y = Y1; }
  else if (blockIdx.y == 2) { W = W2; bias = b2; Y = Y2; }
  gemm_mfma_body<false>(W, Xf, bias, nullptr, Y);
}

__global__ __launch_bounds__(256, 3)
void gemm_silu(const short* __restrict__ Hf, const float* __restrict__ W,
               const float* __restrict__ bias, const float* __restrict__ resid,
               float* __restrict__ Y)
{
  gemm_mfma_body<true>(W, Hf, bias, resid, Y);
}

// attention: unchanged from R0 (next round's target). block = (batch b, 256 i's),
// 1024 threads; thread (i_loc=t&255, jw=t>>8) accumulates s,a over its j-quarter;
// LDS-reduce 4 partials. No max-subtraction: |q*k| <= ~36 << 88.
__global__ __launch_bounds__(1024, 2)
void attn_kernel(const float* __restrict__ q, const float* __restrict__ k,
                 const float* __restrict__ v, const float* __restrict__ X,
                 float* __restrict__ h)
{
  __shared__ __align__(16) float ks[N];
  __shared__ __align__(16) float vs[N];
  __shared__ float red_s[4][256];
  __shared__ float red_a[4][256];
  const int t = threadIdx.x;
  const int wv = t >> 6;
  const int ln = t & 63;
  const int b = blockIdx.x >> 4;
  const int chunk = blockIdx.x & 15;

#if HAVE_ASYNC_LDS
  async_cp16(&k[(size_t)b * N + wv * 256 + 4 * ln], &ks[wv * 256]);
  async_cp16(&v[(size_t)b * N + wv * 256 + 4 * ln], &vs[wv * 256]);
#else
  *(float4*)&ks[wv * 256 + 4 * ln] = *(const float4*)&k[(size_t)b * N + wv * 256 + 4 * ln];
  *(float4*)&vs[wv * 256 + 4 * ln] = *(const float4*)&v[(size_t)b * N + wv * 256 + 4 * ln];
#endif

  const int i_loc = t & 255;
  const int jw = t >> 8;
  const int i = chunk * 256 + i_loc;
  const float qe = q[(size_t)b * N + i] * 1.44269504f;
  __syncthreads();

  const int j0 = jw * 1024;
  float s0 = 0, s1 = 0, s2 = 0, s3 = 0, a0 = 0, a1 = 0, a2 = 0, a3 = 0;
  #pragma unroll 4
  for (int j = j0; j < j0 + 1024; j += 8) {
    float4 ka = *(const float4*)&ks[j];
    float4 va = *(const float4*)&vs[j];
    float4 kb = *(const float4*)&ks[j + 4];
    float4 vb = *(const float4*)&vs[j + 4];
    float e0 = fast_exp2(qe * ka.x);
    float e1 = fast_exp2(qe * ka.y);
    float e2 = fast_exp2(qe * ka.z);
    float e3 = fast_exp2(qe * ka.w);
    float e4 = fast_exp2(qe * kb.x);
    float e5 = fast_exp2(qe * kb.y);
    float e6 = fast_exp2(qe * kb.z);
    float e7 = fast_exp2(qe * kb.w);
    s0 += e0; a0 = fmaf(e0, va.x, a0);
    s1 += e1; a1 = fmaf(e1, va.y, a1);
    s2 += e2; a2 = fmaf(e2, va.z, a2);
    s3 += e3; a3 = fmaf(e3, va.w, a3);
    s0 += e4; a0 = fmaf(e4, vb.x, a0);
    s1 += e5; a1 = fmaf(e5, vb.y, a1);
    s2 += e6; a2 = fmaf(e6, vb.z, a2);
    s3 += e7; a3 = fmaf(e7, vb.w, a3);
  }
  red_s[jw][i_loc] = (s0 + s1) + (s2 + s3);
  red_a[jw][i_loc] = (a0 + a1) + (a2 + a3);
  __syncthreads();

  if (t < 256) {
    float s = ((red_s[0][t] + red_s[1][t]) + (red_s[2][t] + red_s[3][t]));
    float a = ((red_a[0][t] + red_a[1][t]) + (red_a[2][t] + red_a[3][t]));
    int ii = chunk * 256 + t;
    float att = a / s;
    float z = X[(size_t)b * N + ii] + att;
    h[(size_t)b * N + ii] = z / (1.f + fast_exp2(-1.44269504f * z));
  }
}

extern "C" void kernel_launch(void* const* d_in, const int* in_sizes, int n_in,
                              void* d_out, int out_size, void* d_ws, size_t ws_size,
                              hipStream_t stream)
{
  const float* x  = (const float*)d_in[0];
  const float* Wq = (const float*)d_in[1];
  const float* bq = (const float*)d_in[2];
  const float* Wk = (const float*)d_in[3];
  const float* bk = (const float*)d_in[4];
  const float* Wv = (const float*)d_in[5];
  const float* bv = (const float*)d_in[6];
  const float* Wp = (const float*)d_in[7];
  const float* bp = (const float*)d_in[8];
  float* out = (float*)d_out;

  float* q  = (float*)d_ws;          // [32][4096] f32
  float* kk = q  + BATCH * N;
  float* vv = kk + BATCH * N;
  float* h  = vv + BATCH * N;        // 2 MB so far
  short* Xf = (short*)(h + BATCH * N);   // 512 KB frag arrays (x)
  short* Hf = Xf + 4 * 128 * 64 * 8;     // 512 KB frag arrays (h)

  prep_frags<<<dim3(128), 256, 0, stream>>>(x, Xf);
  gemm3<<<dim3(256, 3), 256, 0, stream>>>(Xf, Wq, bq, q, Wk, bk, kk, Wv, bv, vv);
  attn_kernel<<<dim3(BATCH * 16), 1024, 0, stream>>>(q, kk, vv, x, h);
  prep_frags<<<dim3(128), 256, 0, stream>>>(h, Hf);
  gemm_silu<<<dim3(256), 256, 0, stream>>>(Hf, Wp, bp, h, out);
}

// Round 3
// 297.134 us; speedup vs baseline: 1.3744x; 1.2012x over previous
//
#include <hip/hip_runtime.h>
#include <math.h>

#define N 4096
#define BATCH 32

// attn moment method
#define NB 64            // q buckets (= lanes)
#define NP 9             // Taylor terms p=0..8
#define QLO (-10.0f)
#define QBW 0.3125f      // 20/64
#define QINVBW 3.2f
#define NMOM (NB * 2 * NP)   // 1152 floats per batch
#define NCHUNK 8

typedef short bf16x8 __attribute__((ext_vector_type(8)));
typedef float f32x4  __attribute__((ext_vector_type(4)));

static __device__ __forceinline__ float fast_exp2(float x) {
#if __has_builtin(__builtin_amdgcn_exp2f)
  return __builtin_amdgcn_exp2f(x);
#else
  return exp2f(x);
#endif
}

// RNE bf16 (used where cheap/cold); trunc split used in the hot GEMM loop.
static __device__ __forceinline__ unsigned short f2bf_rne(float f) {
  unsigned int u = __float_as_uint(f);
  return (unsigned short)((u + 0x7FFFu + ((u >> 16) & 1u)) >> 16);
}
static __device__ __forceinline__ float bf2f(unsigned short h) {
  return __uint_as_float((unsigned int)h << 16);
}

__device__ const float c_invfact[NP] = {
  1.f, 1.f, 0.5f, 1.f/6.f, 1.f/24.f, 1.f/120.f, 1.f/720.f, 1.f/5040.f, 1.f/40320.f};

// ---------------------------------------------------------------------------
// Fragment-order prep (unchanged from R2, refcheck'd): src [32][4096] f32 ->
// 4 arrays [128 T][64 l][8 j] bf16: narr 0/1 = hi (b 0-15 / 16-31), 2/3 = lo.
// Element (narr,T,l,j) = cvt(src[b=(l&15)|((narr&1)<<4)][k=T*32+(l>>4)*8+j])
// = exactly the B-fragment layout of mfma_f32_16x16x32_bf16.
// ---------------------------------------------------------------------------
__global__ __launch_bounds__(256)
void prep_frags(const float* __restrict__ src, short* __restrict__ dst)
{
  int id = blockIdx.x * 256 + threadIdx.x;
  int narr = id >> 13;
  int rem  = id & 8191;
  int T = rem >> 6;
  int l = rem & 63;
  int b = (l & 15) | ((narr & 1) << 4);
  int k = T * 32 + ((l >> 4) << 3);
  const float* s = &src[(size_t)b * N + k];
  bf16x8 o;
  #pragma unroll
  for (int j = 0; j < 8; ++j) {
    float f = s[j];
    unsigned short h = f2bf_rne(f);
    if (narr >> 1) h = f2bf_rne(f - bf2f(h));
    o[j] = (short)h;
  }
  *(bf16x8*)&dst[(size_t)id * 8] = o;
}

// ---------------------------------------------------------------------------
// MFMA GEMM body. R3 changes vs R2 (which was latency-bound: VGPR=44, 1.2TB/s):
//  - W prefetched in GROUPS of 4 k-steps (8 named float4 = 32 VGPR) while the
//    current group computes -> ~8 outstanding 32B loads/wave. With
//    waves_per_eu(4) (VGPR<=128, body needs ~115) -> 16 waves/CU -> ~4KB W in
//    flight/CU -> ~2.5 TB/s stream (vs 900cy HBM latency).
//  - truncation hi/lo split (4 VALU/elem vs ~8 for RNE); exact residual keeps
//    2^-16 rel representation error.
//  - dropped the al*bl MFMA term (2^-16 rel contribution) -> 6 MFMA/step.
// Wave w covers k in [kbeg + w*NSTEP*32, +NSTEP*32).
// C/D layout (m89): col = l&15 (batch), row = (l>>4)*4 + reg (i offset).
// ---------------------------------------------------------------------------
template <int NSTEP, bool PARTIAL, bool SILU>
__device__ __forceinline__ void gemm_mfma_body(
    const float* __restrict__ W, const short* __restrict__ Xf,
    const float* __restrict__ bias, const float* __restrict__ resid,
    float* __restrict__ Y, int kbeg)
{
  const int t = threadIdx.x;
  const int w = t >> 6, l = t & 63;
  const int i0 = blockIdx.x * 16;

  const float* wrow = &W[(size_t)(i0 + (l & 15)) * N + kbeg + w * (NSTEP * 32) + ((l >> 4) << 3)];
  const short* bbase = Xf + (size_t)((kbeg >> 5) + w * NSTEP) * 512 + l * 8;

  f32x4 acc0 = {0.f, 0.f, 0.f, 0.f};
  f32x4 acc1 = {0.f, 0.f, 0.f, 0.f};

  auto cvt = [&](const float4& a, const float4& b, bf16x8& ah, bf16x8& al) {
    #pragma unroll
    for (int e = 0; e < 8; ++e) {
      float x = (e < 4) ? ((const float*)&a)[e] : ((const float*)&b)[e - 4];
      unsigned int u = __float_as_uint(x);
      ah[e] = (short)(u >> 16);                        // trunc-toward-zero bf16
      float r = x - __uint_as_float(u & 0xFFFF0000u);  // exact residual
      al[e] = (short)(__float_as_uint(r) >> 16);
    }
  };

  auto dostep = [&](const float4& wa, const float4& wb, const short* bptr) {
    bf16x8 bh0 = *(const bf16x8*)(bptr);
    bf16x8 bh1 = *(const bf16x8*)(bptr + 65536);
    bf16x8 bl0 = *(const bf16x8*)(bptr + 131072);
    bf16x8 bl1 = *(const bf16x8*)(bptr + 196608);
    bf16x8 ah, al;
    cvt(wa, wb, ah, al);
    acc0 = __builtin_amdgcn_mfma_f32_16x16x32_bf16(ah, bh0, acc0, 0, 0, 0);
    acc1 = __builtin_amdgcn_mfma_f32_16x16x32_bf16(ah, bh1, acc1, 0, 0, 0);
    acc0 = __builtin_amdgcn_mfma_f32_16x16x32_bf16(ah, bl0, acc0, 0, 0, 0);
    acc1 = __builtin_amdgcn_mfma_f32_16x16x32_bf16(ah, bl1, acc1, 0, 0, 0);
    acc0 = __builtin_amdgcn_mfma_f32_16x16x32_bf16(al, bh0, acc0, 0, 0, 0);
    acc1 = __builtin_amdgcn_mfma_f32_16x16x32_bf16(al, bh1, acc1, 0, 0, 0);
  };

  constexpr int NGRP = NSTEP / 4;
  float4 wc[8], wn[8];
  #pragma unroll
  for (int u = 0; u < 4; ++u) {
    wc[2 * u]     = *(const float4*)(wrow + u * 32);
    wc[2 * u + 1] = *(const float4*)(wrow + u * 32 + 4);
  }
  #pragma unroll 1
  for (int g = 0; g < NGRP - 1; ++g) {
    const float* wg = wrow + (g + 1) * 128;
    #pragma unroll
    for (int u = 0; u < 4; ++u) {
      wn[2 * u]     = *(const float4*)(wg + u * 32);
      wn[2 * u + 1] = *(const float4*)(wg + u * 32 + 4);
    }
    const short* bg = bbase + (size_t)g * 2048;
    #pragma unroll
    for (int u = 0; u < 4; ++u) dostep(wc[2 * u], wc[2 * u + 1], bg + u * 512);
    #pragma unroll
    for (int u = 0; u < 8; ++u) wc[u] = wn[u];
  }
  {
    const short* bg = bbase + (size_t)(NGRP - 1) * 2048;
    #pragma unroll
    for (int u = 0; u < 4; ++u) dostep(wc[2 * u], wc[2 * u + 1], bg + u * 512);
  }

  // cross-wave k-reduction (lane-stride 4B -> conflict-free)
  __shared__ float red[4][2][4][64];   // 8 KB
  #pragma unroll
  for (int r = 0; r < 4; ++r) { red[w][0][r][l] = acc0[r]; red[w][1][r][l] = acc1[r]; }
  __syncthreads();

  #pragma unroll
  for (int e = t; e < 512; e += 256) {
    int b  = e >> 4;
    int il = e & 15;
    int n  = b >> 4;
    int lw = (b & 15) | ((il >> 2) << 4);
    int r  = il & 3;
    float v = ((red[0][n][r][lw] + red[1][n][r][lw]) +
               (red[2][n][r][lw] + red[3][n][r][lw]));
    int i = i0 + il;
    float y = PARTIAL ? v : (v + bias[i]);
    if (SILU) {
      float z = resid[(size_t)b * N + i] + y;
      y = z / (1.f + fast_exp2(-1.44269504f * z));
    }
    Y[(size_t)b * N + i] = y;
  }
}

__global__ __launch_bounds__(256) __attribute__((amdgpu_waves_per_eu(4)))
void gemm3(const short* __restrict__ Xf,
           const float* __restrict__ W0, const float* __restrict__ b0, float* __restrict__ Y0,
           const float* __restrict__ W1, const float* __restrict__ b1, float* __restrict__ Y1,
           const float* __restrict__ W2, const float* __restrict__ b2, float* __restrict__ Y2)
{
  const float* W = W0; const float* bias = b0; float* Y = Y0;
  if (blockIdx.y == 1) { W = W1; bias = b1; Y = Y1; }
  else if (blockIdx.y == 2) { W = W2; bias = b2; Y = Y2; }
  gemm_mfma_body<32, false, false>(W, Xf, bias, nullptr, Y, 0);
}

// Wp GEMM, k-split x4 via blockIdx.y -> 1024 blocks (4/CU, 16 waves/CU).
// Partials land in the dead q/kk/vv buffers + T3; finalize sums them.
__global__ __launch_bounds__(256) __attribute__((amdgpu_waves_per_eu(4)))
void gemm_p(const short* __restrict__ Hf, const float* __restrict__ W,
            float* __restrict__ T0, float* __restrict__ T1,
            float* __restrict__ T2, float* __restrict__ T3)
{
  float* T = T0;
  if (blockIdx.y == 1) T = T1;
  else if (blockIdx.y == 2) T = T2;
  else if (blockIdx.y == 3) T = T3;
  gemm_mfma_body<8, true, false>(W, Hf, nullptr, nullptr, T, blockIdx.y * 1024);
}

// ---------------------------------------------------------------------------
// attn via bucketed Taylor moments. attended_i = g(q_i)/f(q_i) with
// f(q)=sum_j e^{q k_j}, g(q)=sum_j e^{q k_j} v_j. For q in bucket gamma_m:
// f(q) = sum_p d^p * [M_p(gamma)/p!],  M_p = sum_j k^p e^{gamma k},  d=q-gamma.
// 64 buckets over [-10,10] (width .3125), deg 8: |d*k|<=1.25 -> rel tail
// e*1.25^9/9! ~ 7e-5. Exp count: 537M (brute, 86us VALU-bound) -> 8.4M.
// Stage A: grid (b, chunk): 16 waves; lane = bucket; each wave scans 32 j's
// (broadcast k,v), accumulates S[9],T[9] in regs; block-reduce in LDS(73.7KB);
// per-chunk partial to P. Stage B: reduce chunks, fold 1/p!.
// ---------------------------------------------------------------------------
__global__ __launch_bounds__(1024, 2)
void moments_a(const float* __restrict__ kk, const float* __restrict__ vv,
               float* __restrict__ P)
{
  const int b = blockIdx.x, chunk = blockIdx.y;
  const int t = threadIdx.x;
  const int wv = t >> 6, m = t & 63;
  const float gam = QLO + ((float)m + 0.5f) * QBW;
  const float gl2e = gam * 1.44269504f;
  float S[NP], T[NP];
  #pragma unroll
  for (int p = 0; p < NP; ++p) { S[p] = 0.f; T[p] = 0.f; }
  const float* kb = &kk[(size_t)b * N + chunk * 512 + wv * 32];
  const float* vb = &vv[(size_t)b * N + chunk * 512 + wv * 32];
  #pragma unroll 4
  for (int jj = 0; jj < 32; ++jj) {
    float kj = kb[jj];                 // wave-uniform -> broadcast
    float vj = vb[jj];
    float e = fast_exp2(gl2e * kj);
    float tp = e;
    S[0] += tp; T[0] = fmaf(tp, vj, T[0]);
    #pragma unroll
    for (int p = 1; p < NP; ++p) { tp *= kj; S[p] += tp; T[p] = fmaf(tp, vj, T[p]); }
  }
  __shared__ float red[16][NMOM];      // 73.7 KB
  #pragma unroll
  for (int p = 0; p < NP; ++p) {
    red[wv][m * 18 + p] = S[p];        // stride-18: 2-way bank alias = free
    red[wv][m * 18 + NP + p] = T[p];
  }
  __syncthreads();
  for (int e = t; e < NMOM; e += 1024) {
    float s = 0.f;
    #pragma unroll
    for (int w2 = 0; w2 < 16; ++w2) s += red[w2][e];
    P[((size_t)b * NCHUNK + chunk) * NMOM + e] = s;
  }
}

__global__ __launch_bounds__(256)
void moments_b(const float* __restrict__ P, float* __restrict__ M)
{
  int b = blockIdx.x;
  int e = blockIdx.y * 256 + threadIdx.x;
  if (e >= NMOM) return;
  float s = 0.f;
  #pragma unroll
  for (int c = 0; c < NCHUNK; ++c) s += P[((size_t)b * NCHUNK + c) * NMOM + e];
  int p = e % (2 * NP); if (p >= NP) p -= NP;
  M[(size_t)b * NMOM + e] = s * c_invfact[p];   // global const load, no scratch
}

// eval: att = g/f via two deg-8 Horners from LDS-staged moments; fuses
// h = silu(x+att) AND the h->Hf bf16 hi/lo fragment stores (kills prep pass).
__global__ __launch_bounds__(256)
void attn_eval(const float* __restrict__ q, const float* __restrict__ M,
               const float* __restrict__ x, float* __restrict__ h,
               short* __restrict__ Hf)
{
  const int b = blockIdx.x;
  const int i = blockIdx.y * 256 + threadIdx.x;
  __shared__ float cm[NMOM];
  for (int e = threadIdx.x; e < NMOM; e += 256) cm[e] = M[(size_t)b * NMOM + e];
  __syncthreads();
  float qv = q[(size_t)b * N + i];
  float qc = fminf(fmaxf(qv, QLO + 0.01f), -QLO - 0.01f);  // 7.8-sigma guard
  int m = (int)((qc - QLO) * QINVBW);
  float gam = QLO + ((float)m + 0.5f) * QBW;
  float d = qv - gam;
  const float* Sp = &cm[m * 18];
  float f = Sp[NP - 1], g = Sp[2 * NP - 1];
  #pragma unroll
  for (int p = NP - 2; p >= 0; --p) {
    f = fmaf(f, d, Sp[p]);
    g = fmaf(g, d, Sp[NP + p]);
  }
  float att = g / f;
  float z = x[(size_t)b * N + i] + att;
  float hv = z / (1.f + fast_exp2(-1.44269504f * z));
  h[(size_t)b * N + i] = hv;
  unsigned short hi = f2bf_rne(hv);
  unsigned short lo = f2bf_rne(hv - bf2f(hi));
  size_t base = (size_t)(b >> 4) * 65536 + (size_t)(i >> 5) * 512
              + (size_t)((b & 15) | (((i >> 3) & 3) << 4)) * 8 + (size_t)(i & 7);
  Hf[base] = (short)hi;            // hi array (narr 0/1)
  Hf[base + 131072] = (short)lo;   // lo array (narr 2/3)
}

// out = silu(h + (T0+T1+T2+T3) + bp)
__global__ __launch_bounds__(256)
void finalize_kernel(const float* __restrict__ h, const float* __restrict__ T0,
                     const float* __restrict__ T1, const float* __restrict__ T2,
                     const float* __restrict__ T3, const float* __restrict__ bp,
                     float* __restrict__ out)
{
  int idx = (blockIdx.x * 256 + threadIdx.x) * 4;
  int i = idx & (N - 1);
  float4 hv = *(const float4*)&h[idx];
  float4 a  = *(const float4*)&T0[idx];
  float4 b  = *(const float4*)&T1[idx];
  float4 c  = *(const float4*)&T2[idx];
  float4 dd = *(const float4*)&T3[idx];
  float4 bb = *(const float4*)&bp[i];
  float4 z, o;
  z.x = hv.x + (a.x + b.x) + (c.x + dd.x) + bb.x;
  z.y = hv.y + (a.y + b.y) + (c.y + dd.y) + bb.y;
  z.z = hv.z + (a.z + b.z) + (c.z + dd.z) + bb.z;
  z.w = hv.w + (a.w + b.w) + (c.w + dd.w) + bb.w;
  o.x = z.x / (1.f + fast_exp2(-1.44269504f * z.x));
  o.y = z.y / (1.f + fast_exp2(-1.44269504f * z.y));
  o.z = z.z / (1.f + fast_exp2(-1.44269504f * z.z));
  o.w = z.w / (1.f + fast_exp2(-1.44269504f * z.w));
  *(float4*)&out[idx] = o;
}

extern "C" void kernel_launch(void* const* d_in, const int* in_sizes, int n_in,
                              void* d_out, int out_size, void* d_ws, size_t ws_size,
                              hipStream_t stream)
{
  const float* x  = (const float*)d_in[0];
  const float* Wq = (const float*)d_in[1];
  const float* bq = (const float*)d_in[2];
  const float* Wk = (const float*)d_in[3];
  const float* bk = (const float*)d_in[4];
  const float* Wv = (const float*)d_in[5];
  const float* bv = (const float*)d_in[6];
  const float* Wp = (const float*)d_in[7];
  const float* bp = (const float*)d_in[8];
  float* out = (float*)d_out;

  float* q  = (float*)d_ws;              // [32][4096] f32 (later: T0)
  float* kk = q  + BATCH * N;            // (later: T1)
  float* vv = kk + BATCH * N;            // (later: T2)
  float* h  = vv + BATCH * N;
  float* T3 = h  + BATCH * N;
  short* Xf = (short*)(T3 + BATCH * N);  // 512 KB frag arrays (x)
  short* Hf = Xf + 262144;               // 512 KB frag arrays (h)
  float* P  = (float*)(Hf + 262144);     // [32][8][1152] partials
  float* M  = P + (size_t)BATCH * NCHUNK * NMOM;  // [32][1152]

  prep_frags<<<dim3(128), 256, 0, stream>>>(x, Xf);
  gemm3<<<dim3(256, 3), 256, 0, stream>>>(Xf, Wq, bq, q, Wk, bk, kk, Wv, bv, vv);
  moments_a<<<dim3(BATCH, NCHUNK), 1024, 0, stream>>>(kk, vv, P);
  moments_b<<<dim3(BATCH, 5), 256, 0, stream>>>(P, M);
  attn_eval<<<dim3(BATCH, 16), 256, 0, stream>>>(q, M, x, h, Hf);
  gemm_p<<<dim3(256, 4), 256, 0, stream>>>(Hf, Wp, q, kk, vv, T3);
  finalize_kernel<<<dim3(128), 256, 0, stream>>>(h, q, kk, vv, T3, bp, out);
}

// Round 4
// 293.794 us; speedup vs baseline: 1.3900x; 1.0114x over previous
//
#include <hip/hip_runtime.h>
#include <math.h>

#define N 4096
#define BATCH 32

// attn moment method
#define NB 64            // q buckets (= lanes)
#define NP 9             // Taylor terms p=0..8
#define QLO (-10.0f)
#define QBW 0.3125f      // 20/64
#define QINVBW 3.2f
#define NMOM (NB * 2 * NP)   // 1152 floats per batch
#define NCHUNK 8

typedef short bf16x8 __attribute__((ext_vector_type(8)));
typedef float f32x4  __attribute__((ext_vector_type(4)));

static __device__ __forceinline__ float fast_exp2(float x) {
#if __has_builtin(__builtin_amdgcn_exp2f)
  return __builtin_amdgcn_exp2f(x);
#else
  return exp2f(x);
#endif
}

static __device__ __forceinline__ unsigned short f2bf_rne(float f) {
  unsigned int u = __float_as_uint(f);
  return (unsigned short)((u + 0x7FFFu + ((u >> 16) & 1u)) >> 16);
}
static __device__ __forceinline__ float bf2f(unsigned short h) {
  return __uint_as_float((unsigned int)h << 16);
}

__device__ const float c_invfact[NP] = {
  1.f, 1.f, 0.5f, 1.f/6.f, 1.f/24.f, 1.f/120.f, 1.f/720.f, 1.f/5040.f, 1.f/40320.f};

// async global->LDS: lane i writes lds_base + i*16 (wave-uniform LDS base,
// PER-LANE global address). Fallback emulates with lane index.
#if __has_builtin(__builtin_amdgcn_global_load_lds)
#define HAVE_ASYNC_LDS 1
#else
#define HAVE_ASYNC_LDS 0
#endif
static __device__ __forceinline__ void async_cp16(const float* g, float* lds_base, int lane) {
#if HAVE_ASYNC_LDS
  __builtin_amdgcn_global_load_lds(
      (const __attribute__((address_space(1))) void*)g,
      (__attribute__((address_space(3))) void*)lds_base, 16, 0, 0);
#else
  ((float4*)lds_base)[lane] = *(const float4*)g;
#endif
}

// ---------------------------------------------------------------------------
// Fragment-order prep (refcheck'd R2/R3): src [32][4096] f32 ->
// 4 arrays [128 T][64 l][8 j] bf16: narr 0/1 = hi (b 0-15 / 16-31), 2/3 = lo.
// Element (narr,T,l,j) = cvt(src[b=(l&15)|((narr&1)<<4)][k=T*32+(l>>4)*8+j])
// = exactly the B-fragment layout of mfma_f32_16x16x32_bf16.
// ---------------------------------------------------------------------------
__global__ __launch_bounds__(256)
void prep_frags(const float* __restrict__ src, short* __restrict__ dst)
{
  int id = blockIdx.x * 256 + threadIdx.x;
  int narr = id >> 13;
  int rem  = id & 8191;
  int T = rem >> 6;
  int l = rem & 63;
  int b = (l & 15) | ((narr & 1) << 4);
  int k = T * 32 + ((l >> 4) << 3);
  const float* s = &src[(size_t)b * N + k];
  bf16x8 o;
  #pragma unroll
  for (int j = 0; j < 8; ++j) {
    float f = s[j];
    unsigned short h = f2bf_rne(f);
    if (narr >> 1) h = f2bf_rne(f - bf2f(h));
    o[j] = (short)h;
  }
  *(bf16x8*)&dst[(size_t)id * 8] = o;
}

// ---------------------------------------------------------------------------
// MFMA GEMM body, R4: W staged via global_load_lds, wave-private double buffer,
// counted vmcnt. R2/R3 were latency-bound (VGPR-minimized prefetch -> ~2 loads
// in flight -> 1.25 TB/s). One global_load_lds = 1 KB in flight, no VGPR cost;
// 4/tile double-buffered -> 4 KB/wave in flight -> 48 KB/CU >> 8.8 KB BW*lat.
// Staging is FRAGMENT-ORDER: lane l stages W[i0+(l&15)][k + (l>>4)*8 + h*4]
// (its own future A-fragment) -> LDS reads are a linear l*16 sweep, zero
// swizzle. Wave-private LDS -> NO barriers in the K-loop (no vmcnt(0) drain).
// Per tile (64 k): 8 B-frag loads (L2) -> 4 stage(t+1) -> s_waitcnt vmcnt(4)
// (retires bfrags + tile t, keeps t+1 in flight) -> sched_barrier (rule #18)
// -> 2 steps x (ds_read + trunc-split cvt + 6 MFMA; ll term dropped, 2^-16).
// Register discipline: every array static-indexed (scratch ops would corrupt
// the vmcnt count!). C/D layout (m89): col=l&15 (batch), row=(l>>4)*4+reg.
// ---------------------------------------------------------------------------
template <int NTILE, bool PARTIAL>
__device__ __forceinline__ void gemm_mfma_body(
    const float* __restrict__ W, const short* __restrict__ Xf,
    const float* __restrict__ bias, float* __restrict__ Y, int kbeg)
{
  constexpr int NSTEP = NTILE * 2;
  __shared__ __align__(16) union GSm {
    float stg[4][2][1024];       // [wave][buf][4 KB tile], 32 KB
    float red[4][2][4][64];      // epilogue reduce (after syncthreads)
  } sm;
  const int t = threadIdx.x;
  const int w = t >> 6, l = t & 63;
  const int i0 = blockIdx.x * 16;
  const int rr = l & 15, kg = l >> 4;

  // lane's A-fragment source: row i0+rr, k = kbeg + w*NTILE*64 + kg*8 (+tile/step/h)
  const float* wbase = &W[(size_t)(i0 + rr) * N + kbeg + w * (NTILE * 64) + kg * 8];
  const short* bbase = Xf + (size_t)((kbeg >> 5) + w * NSTEP) * 512 + l * 8;

  f32x4 acc0 = {0.f, 0.f, 0.f, 0.f};
  f32x4 acc1 = {0.f, 0.f, 0.f, 0.f};

  // stage tile tt into buf: instr u=(s,h): global +tt*64 +s*32 +h*4, LDS block u*256
  auto stage = [&](int buf, int tt) {
    float* dst = &sm.stg[w][buf][0];
    const float* g = wbase + tt * 64;
    async_cp16(g,      dst,       l);
    async_cp16(g + 4,  dst + 256, l);
    async_cp16(g + 32, dst + 512, l);
    async_cp16(g + 36, dst + 768, l);
  };

  auto cvt = [&](const float4& a, const float4& b, bf16x8& ah, bf16x8& al) {
    #pragma unroll
    for (int e = 0; e < 8; ++e) {
      float x = (e < 4) ? ((const float*)&a)[e] : ((const float*)&b)[e - 4];
      unsigned int u = __float_as_uint(x);
      ah[e] = (short)(u >> 16);                        // trunc bf16
      float r = x - __uint_as_float(u & 0xFFFF0000u);  // exact residual
      al[e] = (short)(__float_as_uint(r) >> 16);
    }
  };

  stage(0, 0);
  int buf = 0;
  #pragma unroll 1
  for (int tt = 0; tt < NTILE; ++tt) {
    // B-frags for both steps of tile tt (L2-resident, coalesced 16 B/lane).
    // Issued BEFORE stage(t+1) so waiting on them never drains the next stage.
    bf16x8 bf0h0 = *(const bf16x8*)(bbase + (size_t)(tt * 2) * 512);
    bf16x8 bf0h1 = *(const bf16x8*)(bbase + (size_t)(tt * 2) * 512 + 65536);
    bf16x8 bf0l0 = *(const bf16x8*)(bbase + (size_t)(tt * 2) * 512 + 131072);
    bf16x8 bf0l1 = *(const bf16x8*)(bbase + (size_t)(tt * 2) * 512 + 196608);
    bf16x8 bf1h0 = *(const bf16x8*)(bbase + (size_t)(tt * 2 + 1) * 512);
    bf16x8 bf1h1 = *(const bf16x8*)(bbase + (size_t)(tt * 2 + 1) * 512 + 65536);
    bf16x8 bf1l0 = *(const bf16x8*)(bbase + (size_t)(tt * 2 + 1) * 512 + 131072);
    bf16x8 bf1l1 = *(const bf16x8*)(bbase + (size_t)(tt * 2 + 1) * 512 + 196608);
    __builtin_amdgcn_sched_barrier(0);
    if (tt + 1 < NTILE) {
      stage(buf ^ 1, tt + 1);
      asm volatile("s_waitcnt vmcnt(4)" ::: "memory");   // tile tt + bfrags retired
    } else {
      asm volatile("s_waitcnt vmcnt(0)" ::: "memory");
    }
    __builtin_amdgcn_sched_barrier(0);

    // step 0
    {
      float4 a0 = *(const float4*)&sm.stg[w][buf][0 * 512 + l * 4];
      float4 a1 = *(const float4*)&sm.stg[w][buf][0 * 512 + 256 + l * 4];
      bf16x8 ah, al;
      cvt(a0, a1, ah, al);
      acc0 = __builtin_amdgcn_mfma_f32_16x16x32_bf16(ah, bf0h0, acc0, 0, 0, 0);
      acc1 = __builtin_amdgcn_mfma_f32_16x16x32_bf16(ah, bf0h1, acc1, 0, 0, 0);
      acc0 = __builtin_amdgcn_mfma_f32_16x16x32_bf16(ah, bf0l0, acc0, 0, 0, 0);
      acc1 = __builtin_amdgcn_mfma_f32_16x16x32_bf16(ah, bf0l1, acc1, 0, 0, 0);
      acc0 = __builtin_amdgcn_mfma_f32_16x16x32_bf16(al, bf0h0, acc0, 0, 0, 0);
      acc1 = __builtin_amdgcn_mfma_f32_16x16x32_bf16(al, bf0h1, acc1, 0, 0, 0);
    }
    // step 1
    {
      float4 a0 = *(const float4*)&sm.stg[w][buf][1 * 512 + l * 4];
      float4 a1 = *(const float4*)&sm.stg[w][buf][1 * 512 + 256 + l * 4];
      bf16x8 ah, al;
      cvt(a0, a1, ah, al);
      acc0 = __builtin_amdgcn_mfma_f32_16x16x32_bf16(ah, bf1h0, acc0, 0, 0, 0);
      acc1 = __builtin_amdgcn_mfma_f32_16x16x32_bf16(ah, bf1h1, acc1, 0, 0, 0);
      acc0 = __builtin_amdgcn_mfma_f32_16x16x32_bf16(ah, bf1l0, acc0, 0, 0, 0);
      acc1 = __builtin_amdgcn_mfma_f32_16x16x32_bf16(ah, bf1l1, acc1, 0, 0, 0);
      acc0 = __builtin_amdgcn_mfma_f32_16x16x32_bf16(al, bf1h0, acc0, 0, 0, 0);
      acc1 = __builtin_amdgcn_mfma_f32_16x16x32_bf16(al, bf1h1, acc1, 0, 0, 0);
    }
    buf ^= 1;
  }
  __syncthreads();   // stg/red union: all LDS tile reads done before red writes

  #pragma unroll
  for (int r = 0; r < 4; ++r) { sm.red[w][0][r][l] = acc0[r]; sm.red[w][1][r][l] = acc1[r]; }
  __syncthreads();

  #pragma unroll
  for (int e = t; e < 512; e += 256) {
    int b  = e >> 4;
    int il = e & 15;
    int n  = b >> 4;
    int lw = (b & 15) | ((il >> 2) << 4);
    int r  = il & 3;
    float v = ((sm.red[0][n][r][lw] + sm.red[1][n][r][lw]) +
               (sm.red[2][n][r][lw] + sm.red[3][n][r][lw]));
    int i = i0 + il;
    Y[(size_t)b * N + i] = PARTIAL ? v : (v + bias[i]);
  }
}

__global__ __launch_bounds__(256) __attribute__((amdgpu_waves_per_eu(4)))
void gemm3(const short* __restrict__ Xf,
           const float* __restrict__ W0, const float* __restrict__ b0, float* __restrict__ Y0,
           const float* __restrict__ W1, const float* __restrict__ b1, float* __restrict__ Y1,
           const float* __restrict__ W2, const float* __restrict__ b2, float* __restrict__ Y2)
{
  const float* W = W0; const float* bias = b0; float* Y = Y0;
  if (blockIdx.y == 1) { W = W1; bias = b1; Y = Y1; }
  else if (blockIdx.y == 2) { W = W2; bias = b2; Y = Y2; }
  gemm_mfma_body<16, false>(W, Xf, bias, Y, 0);
}

// Wp GEMM, k-split x4 (1024 blocks, 4/CU). Partials to dead q/kk/vv + T3.
__global__ __launch_bounds__(256) __attribute__((amdgpu_waves_per_eu(4)))
void gemm_p(const short* __restrict__ Hf, const float* __restrict__ W,
            float* __restrict__ T0, float* __restrict__ T1,
            float* __restrict__ T2, float* __restrict__ T3)
{
  float* T = T0;
  if (blockIdx.y == 1) T = T1;
  else if (blockIdx.y == 2) T = T2;
  else if (blockIdx.y == 3) T = T3;
  gemm_mfma_body<4, true>(W, Hf, nullptr, T, blockIdx.y * 1024);
}

// ---------------------------------------------------------------------------
// attn via bucketed Taylor moments (refcheck'd R3). attended_i = g(q_i)/f(q_i);
// 64 buckets over [-10,10], deg-8 Taylor in d=q-gamma; rel tail ~7e-5.
// ---------------------------------------------------------------------------
__global__ __launch_bounds__(1024, 2)
void moments_a(const float* __restrict__ kk, const float* __restrict__ vv,
               float* __restrict__ P)
{
  const int b = blockIdx.x, chunk = blockIdx.y;
  const int t = threadIdx.x;
  const int wv = t >> 6, m = t & 63;
  const float gam = QLO + ((float)m + 0.5f) * QBW;
  const float gl2e = gam * 1.44269504f;
  float S[NP], T[NP];
  #pragma unroll
  for (int p = 0; p < NP; ++p) { S[p] = 0.f; T[p] = 0.f; }
  const float* kb = &kk[(size_t)b * N + chunk * 512 + wv * 32];
  const float* vb = &vv[(size_t)b * N + chunk * 512 + wv * 32];
  #pragma unroll 4
  for (int jj = 0; jj < 32; ++jj) {
    float kj = kb[jj];
    float vj = vb[jj];
    float e = fast_exp2(gl2e * kj);
    float tp = e;
    S[0] += tp; T[0] = fmaf(tp, vj, T[0]);
    #pragma unroll
    for (int p = 1; p < NP; ++p) { tp *= kj; S[p] += tp; T[p] = fmaf(tp, vj, T[p]); }
  }
  __shared__ float red[16][NMOM];      // 73.7 KB
  #pragma unroll
  for (int p = 0; p < NP; ++p) {
    red[wv][m * 18 + p] = S[p];
    red[wv][m * 18 + NP + p] = T[p];
  }
  __syncthreads();
  for (int e = t; e < NMOM; e += 1024) {
    float s = 0.f;
    #pragma unroll
    for (int w2 = 0; w2 < 16; ++w2) s += red[w2][e];
    P[((size_t)b * NCHUNK + chunk) * NMOM + e] = s;
  }
}

__global__ __launch_bounds__(256)
void moments_b(const float* __restrict__ P, float* __restrict__ M)
{
  int b = blockIdx.x;
  int e = blockIdx.y * 256 + threadIdx.x;
  if (e >= NMOM) return;
  float s = 0.f;
  #pragma unroll
  for (int c = 0; c < NCHUNK; ++c) s += P[((size_t)b * NCHUNK + c) * NMOM + e];
  int p = e % (2 * NP); if (p >= NP) p -= NP;
  M[(size_t)b * NMOM + e] = s * c_invfact[p];
}

// eval: att = g/f via two deg-8 Horners; fuses silu(x+att) AND h->Hf frag stores.
__global__ __launch_bounds__(256)
void attn_eval(const float* __restrict__ q, const float* __restrict__ M,
               const float* __restrict__ x, float* __restrict__ h,
               short* __restrict__ Hf)
{
  const int b = blockIdx.x;
  const int i = blockIdx.y * 256 + threadIdx.x;
  __shared__ float cm[NMOM];
  for (int e = threadIdx.x; e < NMOM; e += 256) cm[e] = M[(size_t)b * NMOM + e];
  __syncthreads();
  float qv = q[(size_t)b * N + i];
  float qc = fminf(fmaxf(qv, QLO + 0.01f), -QLO - 0.01f);
  int m = (int)((qc - QLO) * QINVBW);
  float gam = QLO + ((float)m + 0.5f) * QBW;
  float d = qv - gam;
  const float* Sp = &cm[m * 18];
  float f = Sp[NP - 1], g = Sp[2 * NP - 1];
  #pragma unroll
  for (int p = NP - 2; p >= 0; --p) {
    f = fmaf(f, d, Sp[p]);
    g = fmaf(g, d, Sp[NP + p]);
  }
  float att = g / f;
  float z = x[(size_t)b * N + i] + att;
  float hv = z / (1.f + fast_exp2(-1.44269504f * z));
  h[(size_t)b * N + i] = hv;
  unsigned short hi = f2bf_rne(hv);
  unsigned short lo = f2bf_rne(hv - bf2f(hi));
  size_t base = (size_t)(b >> 4) * 65536 + (size_t)(i >> 5) * 512
              + (size_t)((b & 15) | (((i >> 3) & 3) << 4)) * 8 + (size_t)(i & 7);
  Hf[base] = (short)hi;
  Hf[base + 131072] = (short)lo;
}

// out = silu(h + (T0+T1+T2+T3) + bp)
__global__ __launch_bounds__(256)
void finalize_kernel(const float* __restrict__ h, const float* __restrict__ T0,
                     const float* __restrict__ T1, const float* __restrict__ T2,
                     const float* __restrict__ T3, const float* __restrict__ bp,
                     float* __restrict__ out)
{
  int idx = (blockIdx.x * 256 + threadIdx.x) * 4;
  int i = idx & (N - 1);
  float4 hv = *(const float4*)&h[idx];
  float4 a  = *(const float4*)&T0[idx];
  float4 b  = *(const float4*)&T1[idx];
  float4 c  = *(const float4*)&T2[idx];
  float4 dd = *(const float4*)&T3[idx];
  float4 bb = *(const float4*)&bp[i];
  float4 z, o;
  z.x = hv.x + (a.x + b.x) + (c.x + dd.x) + bb.x;
  z.y = hv.y + (a.y + b.y) + (c.y + dd.y) + bb.y;
  z.z = hv.z + (a.z + b.z) + (c.z + dd.z) + bb.z;
  z.w = hv.w + (a.w + b.w) + (c.w + dd.w) + bb.w;
  o.x = z.x / (1.f + fast_exp2(-1.44269504f * z.x));
  o.y = z.y / (1.f + fast_exp2(-1.44269504f * z.y));
  o.z = z.z / (1.f + fast_exp2(-1.44269504f * z.z));
  o.w = z.w / (1.f + fast_exp2(-1.44269504f * z.w));
  *(float4*)&out[idx] = o;
}

extern "C" void kernel_launch(void* const* d_in, const int* in_sizes, int n_in,
                              void* d_out, int out_size, void* d_ws, size_t ws_size,
                              hipStream_t stream)
{
  const float* x  = (const float*)d_in[0];
  const float* Wq = (const float*)d_in[1];
  const float* bq = (const float*)d_in[2];
  const float* Wk = (const float*)d_in[3];
  const float* bk = (const float*)d_in[4];
  const float* Wv = (const float*)d_in[5];
  const float* bv = (const float*)d_in[6];
  const float* Wp = (const float*)d_in[7];
  const float* bp = (const float*)d_in[8];
  float* out = (float*)d_out;

  float* q  = (float*)d_ws;              // [32][4096] f32 (later: T0)
  float* kk = q  + BATCH * N;            // (later: T1)
  float* vv = kk + BATCH * N;            // (later: T2)
  float* h  = vv + BATCH * N;
  float* T3 = h  + BATCH * N;
  short* Xf = (short*)(T3 + BATCH * N);  // 512 KB frag arrays (x)
  short* Hf = Xf + 262144;               // 512 KB frag arrays (h)
  float* P  = (float*)(Hf + 262144);     // [32][8][1152] partials
  float* M  = P + (size_t)BATCH * NCHUNK * NMOM;  // [32][1152]

  prep_frags<<<dim3(128), 256, 0, stream>>>(x, Xf);
  gemm3<<<dim3(256, 3), 256, 0, stream>>>(Xf, Wq, bq, q, Wk, bk, kk, Wv, bv, vv);
  moments_a<<<dim3(BATCH, NCHUNK), 1024, 0, stream>>>(kk, vv, P);
  moments_b<<<dim3(BATCH, 5), 256, 0, stream>>>(P, M);
  attn_eval<<<dim3(BATCH, 16), 256, 0, stream>>>(q, M, x, h, Hf);
  gemm_p<<<dim3(256, 4), 256, 0, stream>>>(Hf, Wp, q, kk, vv, T3);
  finalize_kernel<<<dim3(128), 256, 0, stream>>>(h, q, kk, vv, T3, bp, out);
}

// Round 5
// 285.297 us; speedup vs baseline: 1.4314x; 1.0298x over previous
//
#include <hip/hip_runtime.h>
#include <math.h>

#define N 4096
#define BATCH 32

// attn moment method
#define NB 64            // q buckets (= lanes)
#define NP 9             // Taylor terms p=0..8
#define QLO (-10.0f)
#define QBW 0.3125f      // 20/64
#define QINVBW 3.2f
#define NMOM (NB * 2 * NP)   // 1152 floats per batch
#define NCHUNK 8

typedef short bf16x8 __attribute__((ext_vector_type(8)));
typedef float f32x4  __attribute__((ext_vector_type(4)));

static __device__ __forceinline__ float fast_exp2(float x) {
#if __has_builtin(__builtin_amdgcn_exp2f)
  return __builtin_amdgcn_exp2f(x);
#else
  return exp2f(x);
#endif
}

static __device__ __forceinline__ unsigned short f2bf_rne(float f) {
  unsigned int u = __float_as_uint(f);
  return (unsigned short)((u + 0x7FFFu + ((u >> 16) & 1u)) >> 16);
}
static __device__ __forceinline__ float bf2f(unsigned short h) {
  return __uint_as_float((unsigned int)h << 16);
}

__device__ const float c_invfact[NP] = {
  1.f, 1.f, 0.5f, 1.f/6.f, 1.f/24.f, 1.f/120.f, 1.f/720.f, 1.f/5040.f, 1.f/40320.f};

// ---------------------------------------------------------------------------
// Fragment-order prep (refcheck'd R2-R4): src [32][4096] f32 ->
// 4 arrays [128 T][64 l][8 j] bf16: narr 0/1 = hi (b 0-15 / 16-31), 2/3 = lo.
// Element (narr,T,l,j) = cvt(src[b=(l&15)|((narr&1)<<4)][k=T*32+(l>>4)*8+j])
// = exactly the B-fragment layout of mfma_f32_16x16x32_bf16.
// ---------------------------------------------------------------------------
__global__ __launch_bounds__(256)
void prep_frags(const float* __restrict__ src, short* __restrict__ dst)
{
  int id = blockIdx.x * 256 + threadIdx.x;
  int narr = id >> 13;
  int rem  = id & 8191;
  int T = rem >> 6;
  int l = rem & 63;
  int b = (l & 15) | ((narr & 1) << 4);
  int k = T * 32 + ((l >> 4) << 3);
  const float* s = &src[(size_t)b * N + k];
  bf16x8 o;
  #pragma unroll
  for (int j = 0; j < 8; ++j) {
    float f = s[j];
    unsigned short h = f2bf_rne(f);
    if (narr >> 1) h = f2bf_rne(f - bf2f(h));
    o[j] = (short)h;
  }
  *(bf16x8*)&dst[(size_t)id * 8] = o;
}

// ---------------------------------------------------------------------------
// MFMA GEMM body, R5. Diagnosis from R2/R3/R4: streaming BW scales with
// RESIDENT WAVES (~0.5-0.85 GB/s each; R1 3.5w->0.76 TB/s, R2-R4 ~9w->1.25,
// m13 copy ~32w->6.3), NOT with per-wave in-flight depth (R2 2-load vs R4
// 12KB staged: identical BW). So: lean compiler-scheduled body (VGPR 44<=64
// -> 8 waves/SIMD allowed), 512-thr blocks (8 waves k-split in-block, 16KB
// LDS reduce), enough blocks for 4 resident/CU = 32 waves/CU.
// W streams straight to registers (each element read once); B-frags from the
// L2-resident Xf arrays; trunc hi/lo split, ll term dropped (2^-16 rel).
// Output is a k-slice PARTIAL (no bias) - biases folded into consumers.
// C/D layout (m89): col=l&15 (batch), row=(l>>4)*4+reg (i offset).
// ---------------------------------------------------------------------------
template <int NSTEP, int NWAVES>
__device__ __forceinline__ void gemm_mfma_body(
    const float* __restrict__ W, const short* __restrict__ Xf,
    float* __restrict__ Y, int kbeg)
{
  const int t = threadIdx.x;
  const int w = t >> 6, l = t & 63;
  const int i0 = blockIdx.x * 16;

  const float* wrow = &W[(size_t)(i0 + (l & 15)) * N + kbeg + w * (NSTEP * 32) + ((l >> 4) << 3)];
  const short* bbase = Xf + (size_t)((kbeg >> 5) + w * NSTEP) * 512 + l * 8;

  f32x4 acc0 = {0.f, 0.f, 0.f, 0.f};
  f32x4 acc1 = {0.f, 0.f, 0.f, 0.f};

  #pragma unroll 4
  for (int s = 0; s < NSTEP; ++s) {
    float4 wa = *(const float4*)(wrow + s * 32);
    float4 wb = *(const float4*)(wrow + s * 32 + 4);
    bf16x8 bh0 = *(const bf16x8*)(bbase + (size_t)s * 512);
    bf16x8 bh1 = *(const bf16x8*)(bbase + (size_t)s * 512 + 65536);
    bf16x8 bl0 = *(const bf16x8*)(bbase + (size_t)s * 512 + 131072);
    bf16x8 bl1 = *(const bf16x8*)(bbase + (size_t)s * 512 + 196608);
    bf16x8 ah, al;
    #pragma unroll
    for (int e = 0; e < 8; ++e) {
      float x = (e < 4) ? ((const float*)&wa)[e] : ((const float*)&wb)[e - 4];
      unsigned int u = __float_as_uint(x);
      ah[e] = (short)(u >> 16);                        // trunc bf16
      float r = x - __uint_as_float(u & 0xFFFF0000u);  // exact residual
      al[e] = (short)(__float_as_uint(r) >> 16);
    }
    acc0 = __builtin_amdgcn_mfma_f32_16x16x32_bf16(ah, bh0, acc0, 0, 0, 0);
    acc1 = __builtin_amdgcn_mfma_f32_16x16x32_bf16(ah, bh1, acc1, 0, 0, 0);
    acc0 = __builtin_amdgcn_mfma_f32_16x16x32_bf16(ah, bl0, acc0, 0, 0, 0);
    acc1 = __builtin_amdgcn_mfma_f32_16x16x32_bf16(ah, bl1, acc1, 0, 0, 0);
    acc0 = __builtin_amdgcn_mfma_f32_16x16x32_bf16(al, bh0, acc0, 0, 0, 0);
    acc1 = __builtin_amdgcn_mfma_f32_16x16x32_bf16(al, bh1, acc1, 0, 0, 0);
  }

  // cross-wave k-reduction (lane-stride 4B -> conflict-free). 16 KB for 8 waves.
  __shared__ float red[NWAVES][2][4][64];
  #pragma unroll
  for (int r = 0; r < 4; ++r) { red[w][0][r][l] = acc0[r]; red[w][1][r][l] = acc1[r]; }
  __syncthreads();

  #pragma unroll
  for (int e = t; e < 512; e += NWAVES * 64) {
    int b  = e >> 4;
    int il = e & 15;
    int n  = b >> 4;
    int lw = (b & 15) | ((il >> 2) << 4);
    int r  = il & 3;
    float v = 0.f;
    #pragma unroll
    for (int w2 = 0; w2 < NWAVES; ++w2) v += red[w2][n][r][lw];
    Y[(size_t)b * N + i0 + il] = v;
  }
}

// q/k/v GEMMs: grid (256, 6): y>>1 = matrix, y&1 = k-slice (2048 k per block).
// 1536 blocks x 512 thr -> 4 resident blocks/CU = 32 waves/CU (VGPR<=64, LDS 16KB).
__global__ __launch_bounds__(512) __attribute__((amdgpu_waves_per_eu(8)))
void gemm3(const short* __restrict__ Xf,
           const float* __restrict__ W0, const float* __restrict__ W1,
           const float* __restrict__ W2, float* __restrict__ GP)
{
  int m = blockIdx.y >> 1;
  const float* W = (m == 0) ? W0 : (m == 1) ? W1 : W2;
  gemm_mfma_body<8, 8>(W, Xf, GP + (size_t)blockIdx.y * (BATCH * N), (blockIdx.y & 1) * 2048);
}

// Wp GEMM: grid (256, 4): y = k-slice (1024 k per block). GP slots 0..3 (dead
// after attn_eval). 1024 blocks -> 4/CU = 32 waves/CU.
__global__ __launch_bounds__(512) __attribute__((amdgpu_waves_per_eu(8)))
void gemm_p(const short* __restrict__ Hf, const float* __restrict__ W,
            float* __restrict__ GP)
{
  gemm_mfma_body<4, 8>(W, Hf, GP + (size_t)blockIdx.y * (BATCH * N), blockIdx.y * 1024);
}

// ---------------------------------------------------------------------------
// attn via bucketed Taylor moments (refcheck'd R3/R4). attended_i = g/f;
// 64 buckets over [-10,10], deg-8 Taylor in d=q-gamma; rel tail ~7e-5.
// R5: k,v slice-reduction + bias FUSED: block stages k/v chunk into LDS from
// the two GP partials + bias (coalesced), then the moment loop reads LDS.
// ---------------------------------------------------------------------------
__global__ __launch_bounds__(1024, 2)
void moments_a(const float* __restrict__ GP, const float* __restrict__ bk,
               const float* __restrict__ bv, float* __restrict__ P)
{
  const int b = blockIdx.x, chunk = blockIdx.y;
  const int t = threadIdx.x;
  const int wv = t >> 6, m = t & 63;

  __shared__ float ksm[512], vsm[512];
  {
    const float* GP2 = GP + (size_t)2 * BATCH * N;
    const float* GP3 = GP + (size_t)3 * BATCH * N;
    const float* GP4 = GP + (size_t)4 * BATCH * N;
    const float* GP5 = GP + (size_t)5 * BATCH * N;
    int col = chunk * 512 + (t & 511);
    size_t o = (size_t)b * N + col;
    if (t < 512) ksm[t] = GP2[o] + GP3[o] + bk[col];
    else         vsm[t & 511] = GP4[o] + GP5[o] + bv[col];
  }
  __syncthreads();

  const float gam = QLO + ((float)m + 0.5f) * QBW;
  const float gl2e = gam * 1.44269504f;
  float S[NP], T[NP];
  #pragma unroll
  for (int p = 0; p < NP; ++p) { S[p] = 0.f; T[p] = 0.f; }
  const int jb = wv * 32;
  #pragma unroll 4
  for (int jj = 0; jj < 32; ++jj) {
    float kj = ksm[jb + jj];           // wave-uniform -> LDS broadcast
    float vj = vsm[jb + jj];
    float e = fast_exp2(gl2e * kj);
    float tp = e;
    S[0] += tp; T[0] = fmaf(tp, vj, T[0]);
    #pragma unroll
    for (int p = 1; p < NP; ++p) { tp *= kj; S[p] += tp; T[p] = fmaf(tp, vj, T[p]); }
  }
  __shared__ float red[16][NMOM];      // 73.7 KB (+4 KB ksm/vsm = 77.7 <= 80)
  #pragma unroll
  for (int p = 0; p < NP; ++p) {
    red[wv][m * 18 + p] = S[p];        // stride-18: 2-way bank alias = free
    red[wv][m * 18 + NP + p] = T[p];
  }
  __syncthreads();
  for (int e = t; e < NMOM; e += 1024) {
    float s = 0.f;
    #pragma unroll
    for (int w2 = 0; w2 < 16; ++w2) s += red[w2][e];
    P[((size_t)b * NCHUNK + chunk) * NMOM + e] = s;
  }
}

// eval: att = g/f via two deg-8 Horners. Fuses: q slice-sum + bias; P chunk
// reduction * 1/p! (was moments_b); silu(x+att) -> h; h -> Hf bf16 frag stores.
__global__ __launch_bounds__(256)
void attn_eval(const float* __restrict__ GP, const float* __restrict__ bq,
               const float* __restrict__ P, const float* __restrict__ x,
               float* __restrict__ h, short* __restrict__ Hf)
{
  const int b = blockIdx.x;
  const int i = blockIdx.y * 256 + threadIdx.x;
  __shared__ float cm[NMOM];
  for (int e = threadIdx.x; e < NMOM; e += 256) {
    float s = 0.f;
    #pragma unroll
    for (int c = 0; c < NCHUNK; ++c) s += P[((size_t)b * NCHUNK + c) * NMOM + e];
    int p = e % (2 * NP); if (p >= NP) p -= NP;
    cm[e] = s * c_invfact[p];
  }
  __syncthreads();
  size_t o = (size_t)b * N + i;
  float qv = GP[o] + GP[(size_t)BATCH * N + o] + bq[i];
  float qc = fminf(fmaxf(qv, QLO + 0.01f), -QLO - 0.01f);
  int m = (int)((qc - QLO) * QINVBW);
  float gam = QLO + ((float)m + 0.5f) * QBW;
  float d = qv - gam;
  const float* Sp = &cm[m * 18];
  float f = Sp[NP - 1], g = Sp[2 * NP - 1];
  #pragma unroll
  for (int p = NP - 2; p >= 0; --p) {
    f = fmaf(f, d, Sp[p]);
    g = fmaf(g, d, Sp[NP + p]);
  }
  float att = g / f;
  float z = x[o] + att;
  float hv = z / (1.f + fast_exp2(-1.44269504f * z));
  h[o] = hv;
  unsigned short hi = f2bf_rne(hv);
  unsigned short lo = f2bf_rne(hv - bf2f(hi));
  size_t base = (size_t)(b >> 4) * 65536 + (size_t)(i >> 5) * 512
              + (size_t)((b & 15) | (((i >> 3) & 3) << 4)) * 8 + (size_t)(i & 7);
  Hf[base] = (short)hi;
  Hf[base + 131072] = (short)lo;
}

// out = silu(h + (GP0+GP1+GP2+GP3) + bp)
__global__ __launch_bounds__(256)
void finalize_kernel(const float* __restrict__ h, const float* __restrict__ GP,
                     const float* __restrict__ bp, float* __restrict__ out)
{
  int idx = (blockIdx.x * 256 + threadIdx.x) * 4;
  int i = idx & (N - 1);
  const float* T0 = GP;
  const float* T1 = GP + (size_t)1 * BATCH * N;
  const float* T2 = GP + (size_t)2 * BATCH * N;
  const float* T3 = GP + (size_t)3 * BATCH * N;
  float4 hv = *(const float4*)&h[idx];
  float4 a  = *(const float4*)&T0[idx];
  float4 bb2 = *(const float4*)&T1[idx];
  float4 c  = *(const float4*)&T2[idx];
  float4 dd = *(const float4*)&T3[idx];
  float4 bb = *(const float4*)&bp[i];
  float4 z, o;
  z.x = hv.x + (a.x + bb2.x) + (c.x + dd.x) + bb.x;
  z.y = hv.y + (a.y + bb2.y) + (c.y + dd.y) + bb.y;
  z.z = hv.z + (a.z + bb2.z) + (c.z + dd.z) + bb.z;
  z.w = hv.w + (a.w + bb2.w) + (c.w + dd.w) + bb.w;
  o.x = z.x / (1.f + fast_exp2(-1.44269504f * z.x));
  o.y = z.y / (1.f + fast_exp2(-1.44269504f * z.y));
  o.z = z.z / (1.f + fast_exp2(-1.44269504f * z.z));
  o.w = z.w / (1.f + fast_exp2(-1.44269504f * z.w));
  *(float4*)&out[idx] = o;
}

extern "C" void kernel_launch(void* const* d_in, const int* in_sizes, int n_in,
                              void* d_out, int out_size, void* d_ws, size_t ws_size,
                              hipStream_t stream)
{
  const float* x  = (const float*)d_in[0];
  const float* Wq = (const float*)d_in[1];
  const float* bq = (const float*)d_in[2];
  const float* Wk = (const float*)d_in[3];
  const float* bk = (const float*)d_in[4];
  const float* Wv = (const float*)d_in[5];
  const float* bv = (const float*)d_in[6];
  const float* Wp = (const float*)d_in[7];
  const float* bp = (const float*)d_in[8];
  float* out = (float*)d_out;

  float* GP = (float*)d_ws;                        // 6 x [32][4096] f32 partials (3 MB)
  float* h  = GP + (size_t)6 * BATCH * N;          // [32][4096]
  short* Xf = (short*)(h + BATCH * N);             // 512 KB frag arrays (x)
  short* Hf = Xf + 262144;                         // 512 KB frag arrays (h)
  float* P  = (float*)(Hf + 262144);               // [32][8][1152] moment partials

  prep_frags<<<dim3(128), 256, 0, stream>>>(x, Xf);
  gemm3<<<dim3(256, 6), 512, 0, stream>>>(Xf, Wq, Wk, Wv, GP);
  moments_a<<<dim3(BATCH, NCHUNK), 1024, 0, stream>>>(GP, bk, bv, P);
  attn_eval<<<dim3(BATCH, 16), 256, 0, stream>>>(GP, bq, P, x, h, Hf);
  gemm_p<<<dim3(256, 4), 512, 0, stream>>>(Hf, Wp, GP);
  finalize_kernel<<<dim3(128), 256, 0, stream>>>(h, GP, bp, out);
}

// Round 6
// 273.111 us; speedup vs baseline: 1.4953x; 1.0446x over previous
//
#include <hip/hip_runtime.h>
#include <math.h>

#define N 4096
#define BATCH 32

// attn moment method
#define NB 64            // q buckets (= lanes)
#define NP 9             // Taylor terms p=0..8
#define QLO (-10.0f)
#define QBW 0.3125f      // 20/64
#define QINVBW 3.2f
#define NMOM (NB * 2 * NP)   // 1152 floats per batch
#define NCHUNK 8

typedef short bf16x8 __attribute__((ext_vector_type(8)));
typedef float f32x4  __attribute__((ext_vector_type(4)));

static __device__ __forceinline__ float fast_exp2(float x) {
#if __has_builtin(__builtin_amdgcn_exp2f)
  return __builtin_amdgcn_exp2f(x);
#else
  return exp2f(x);
#endif
}

static __device__ __forceinline__ unsigned short f2bf_rne(float f) {
  unsigned int u = __float_as_uint(f);
  return (unsigned short)((u + 0x7FFFu + ((u >> 16) & 1u)) >> 16);
}
static __device__ __forceinline__ float bf2f(unsigned short h) {
  return __uint_as_float((unsigned int)h << 16);
}

__device__ const float c_invfact[NP] = {
  1.f, 1.f, 0.5f, 1.f/6.f, 1.f/24.f, 1.f/120.f, 1.f/720.f, 1.f/5040.f, 1.f/40320.f};

// async global->LDS: lane i writes lds_base + i*16 (wave-uniform LDS base,
// PER-LANE global address).
#if __has_builtin(__builtin_amdgcn_global_load_lds)
#define HAVE_ASYNC_LDS 1
#else
#define HAVE_ASYNC_LDS 0
#endif
static __device__ __forceinline__ void async_cp16(const float* g, float* lds_base, int lane) {
#if HAVE_ASYNC_LDS
  __builtin_amdgcn_global_load_lds(
      (const __attribute__((address_space(1))) void*)g,
      (__attribute__((address_space(3))) void*)lds_base, 16, 0, 0);
#else
  ((float4*)lds_base)[lane] = *(const float4*)g;
#endif
}

// ---------------------------------------------------------------------------
// Fragment-order prep (refcheck'd R2-R5): src [32][4096] f32 ->
// 4 arrays [128 T][64 l][8 j] bf16: narr 0/1 = hi (b 0-15 / 16-31), 2/3 = lo.
// Element (narr,T,l,j) = cvt(src[b=(l&15)|((narr&1)<<4)][k=T*32+(l>>4)*8+j])
// = exactly the B-fragment layout of mfma_f32_16x16x32_bf16.
// ---------------------------------------------------------------------------
__global__ __launch_bounds__(256)
void prep_frags(const float* __restrict__ src, short* __restrict__ dst)
{
  int id = blockIdx.x * 256 + threadIdx.x;
  int narr = id >> 13;
  int rem  = id & 8191;
  int T = rem >> 6;
  int l = rem & 63;
  int b = (l & 15) | ((narr & 1) << 4);
  int k = T * 32 + ((l >> 4) << 3);
  const float* s = &src[(size_t)b * N + k];
  bf16x8 o;
  #pragma unroll
  for (int j = 0; j < 8; ++j) {
    float f = s[j];
    unsigned short h = f2bf_rne(f);
    if (narr >> 1) h = f2bf_rne(f - bf2f(h));
    o[j] = (short)h;
  }
  *(bf16x8*)&dst[(size_t)id * 8] = o;
}

// ---------------------------------------------------------------------------
// MFMA GEMM body, R6. Diagnosis from R2-R5: the 1.2-1.35 TB/s plateau is the
// W ACCESS PATTERN (lane l -> row l&15: 32 scattered 64-B lines per wave
// instruction at 16-KB row stride), invariant under occupancy (27->69%) and
// per-wave in-flight depth (2 loads vs 12 KB staged). Fix: every W load is a
// CONTIGUOUS 1-KB burst (one row's 256-float chunk per global_load_lds, lane l
// -> +4l floats), redistributed to fragment order via a shared double-buffered
// LDS tile [16 rows][256 k] (32 KB). Wave w stages rows 2w,2w+1 of tile t+1,
// computes k-step w of tile t (k-step-split across 8 waves; cross-wave reduce
// at the end). The A-frag ds_read is 16-way bank-conflicted but is 2 reads per
// ~2us memory phase - irrelevant; no swizzle (keeps global_load_lds legal,
// m104). One __syncthreads per tile; its vmcnt(0) drain IS the next tile's
// stage, covered by 3 blocks/CU TLP (grid 768 = exactly one round).
// C/D layout (m89): col=l&15 (batch), row=(l>>4)*4+reg (i offset).
// ---------------------------------------------------------------------------
template <int NTILE, bool FINAL>
__device__ __forceinline__ void gemm_mfma_body(
    const float* __restrict__ W, const short* __restrict__ Xf,
    const float* __restrict__ bias, float* __restrict__ Y, int kbeg)
{
  __shared__ __align__(16) union GSm {
    float stg[2][16][256];     // 32 KB: double-buffered W tile (row-major, linear)
    float red[8][2][4][64];    // 16 KB: epilogue cross-wave reduce
  } sm;
  const int t = threadIdx.x;
  const int w = t >> 6, l = t & 63;
  const int i0 = blockIdx.x * 16;

  // contiguous staging sources: wave w owns rows 2w, 2w+1
  const float* gsrc0 = &W[(size_t)(i0 + 2 * w)     * N + kbeg + 4 * l];
  const float* gsrc1 = &W[(size_t)(i0 + 2 * w + 1) * N + kbeg + 4 * l];
  // B frags: T-step index = (kbeg>>5) + tt*8 + w
  const short* bbase = Xf + (size_t)(kbeg >> 5) * 512 + l * 8;

  f32x4 acc0 = {0.f, 0.f, 0.f, 0.f};
  f32x4 acc1 = {0.f, 0.f, 0.f, 0.f};

  auto stage = [&](int buf, int tt) {
    async_cp16(gsrc0 + tt * 256, &sm.stg[buf][2 * w][0], l);
    async_cp16(gsrc1 + tt * 256, &sm.stg[buf][2 * w + 1][0], l);
  };

  stage(0, 0);
  __syncthreads();
  int buf = 0;
  #pragma unroll 1
  for (int tt = 0; tt < NTILE; ++tt) {
    if (tt + 1 < NTILE) stage(buf ^ 1, tt + 1);
    const short* bp = bbase + (size_t)(tt * 8 + w) * 512;
    bf16x8 bh0 = *(const bf16x8*)(bp);
    bf16x8 bh1 = *(const bf16x8*)(bp + 65536);
    bf16x8 bl0 = *(const bf16x8*)(bp + 131072);
    bf16x8 bl1 = *(const bf16x8*)(bp + 196608);
    // A frag: row l&15, floats w*32 + (l>>4)*8 within tile
    const float* ap = &sm.stg[buf][l & 15][w * 32 + ((l >> 4) << 3)];
    float4 a0 = *(const float4*)ap;
    float4 a1 = *(const float4*)(ap + 4);
    bf16x8 ah, al;
    #pragma unroll
    for (int e = 0; e < 8; ++e) {
      float x = (e < 4) ? ((const float*)&a0)[e] : ((const float*)&a1)[e - 4];
      unsigned int u = __float_as_uint(x);
      ah[e] = (short)(u >> 16);                        // trunc bf16
      float r = x - __uint_as_float(u & 0xFFFF0000u);  // exact residual
      al[e] = (short)(__float_as_uint(r) >> 16);
    }
    acc0 = __builtin_amdgcn_mfma_f32_16x16x32_bf16(ah, bh0, acc0, 0, 0, 0);
    acc1 = __builtin_amdgcn_mfma_f32_16x16x32_bf16(ah, bh1, acc1, 0, 0, 0);
    acc0 = __builtin_amdgcn_mfma_f32_16x16x32_bf16(ah, bl0, acc0, 0, 0, 0);
    acc1 = __builtin_amdgcn_mfma_f32_16x16x32_bf16(ah, bl1, acc1, 0, 0, 0);
    acc0 = __builtin_amdgcn_mfma_f32_16x16x32_bf16(al, bh0, acc0, 0, 0, 0);
    acc1 = __builtin_amdgcn_mfma_f32_16x16x32_bf16(al, bh1, acc1, 0, 0, 0);
    __syncthreads();   // next tile staged (all waves) + this tile's reads done
    buf ^= 1;
  }

  // cross-wave k-step reduction (union with stg: barrier above protects)
  #pragma unroll
  for (int r = 0; r < 4; ++r) { sm.red[w][0][r][l] = acc0[r]; sm.red[w][1][r][l] = acc1[r]; }
  __syncthreads();

  {
    int e  = t;                    // 512 threads, 512 outputs
    int b  = e >> 4;
    int il = e & 15;
    int n  = b >> 4;
    int lw = (b & 15) | ((il >> 2) << 4);
    int r  = il & 3;
    float v = 0.f;
    #pragma unroll
    for (int w2 = 0; w2 < 8; ++w2) v += sm.red[w2][n][r][lw];
    int i = i0 + il;
    Y[(size_t)b * N + i] = FINAL ? (v + bias[i]) : v;
  }
}

// q/k/v GEMMs: grid (256,3) = 768 blocks x 512 thr = exactly 3 blocks/CU.
// Full K per block -> writes FINAL q/k/v incl. bias.
__global__ __launch_bounds__(512)
void gemm3(const short* __restrict__ Xf,
           const float* __restrict__ W0, const float* __restrict__ b0, float* __restrict__ Y0,
           const float* __restrict__ W1, const float* __restrict__ b1, float* __restrict__ Y1,
           const float* __restrict__ W2, const float* __restrict__ b2, float* __restrict__ Y2)
{
  const float* W = W0; const float* bias = b0; float* Y = Y0;
  if (blockIdx.y == 1) { W = W1; bias = b1; Y = Y1; }
  else if (blockIdx.y == 2) { W = W2; bias = b2; Y = Y2; }
  gemm_mfma_body<16, true>(W, Xf, bias, Y, 0);
}

// Wp GEMM: grid (256,2), k-split x2 -> partials GP0/GP1 (summed in finalize).
__global__ __launch_bounds__(512)
void gemm_p(const short* __restrict__ Hf, const float* __restrict__ W,
            float* __restrict__ GP)
{
  gemm_mfma_body<8, false>(W, Hf, nullptr, GP + (size_t)blockIdx.y * (BATCH * N),
                           blockIdx.y * 2048);
}

// ---------------------------------------------------------------------------
// attn via bucketed Taylor moments (refcheck'd R3-R5). attended_i = g/f;
// 64 buckets over [-10,10], deg-8 Taylor in d=q-gamma; rel tail ~7e-5.
// Reads final kk/vv (bias already folded by gemm3).
// ---------------------------------------------------------------------------
__global__ __launch_bounds__(1024, 2)
void moments_a(const float* __restrict__ kk, const float* __restrict__ vv,
               float* __restrict__ P)
{
  const int b = blockIdx.x, chunk = blockIdx.y;
  const int t = threadIdx.x;
  const int wv = t >> 6, m = t & 63;
  const float gam = QLO + ((float)m + 0.5f) * QBW;
  const float gl2e = gam * 1.44269504f;
  float S[NP], T[NP];
  #pragma unroll
  for (int p = 0; p < NP; ++p) { S[p] = 0.f; T[p] = 0.f; }
  const float* kb = &kk[(size_t)b * N + chunk * 512 + wv * 32];
  const float* vb = &vv[(size_t)b * N + chunk * 512 + wv * 32];
  #pragma unroll 4
  for (int jj = 0; jj < 32; ++jj) {
    float kj = kb[jj];                 // wave-uniform -> broadcast
    float vj = vb[jj];
    float e = fast_exp2(gl2e * kj);
    float tp = e;
    S[0] += tp; T[0] = fmaf(tp, vj, T[0]);
    #pragma unroll
    for (int p = 1; p < NP; ++p) { tp *= kj; S[p] += tp; T[p] = fmaf(tp, vj, T[p]); }
  }
  __shared__ float red[16][NMOM];      // 73.7 KB
  #pragma unroll
  for (int p = 0; p < NP; ++p) {
    red[wv][m * 18 + p] = S[p];        // stride-18: 2-way bank alias = free
    red[wv][m * 18 + NP + p] = T[p];
  }
  __syncthreads();
  for (int e = t; e < NMOM; e += 1024) {
    float s = 0.f;
    #pragma unroll
    for (int w2 = 0; w2 < 16; ++w2) s += red[w2][e];
    P[((size_t)b * NCHUNK + chunk) * NMOM + e] = s;
  }
}

// eval: att = g/f via two deg-8 Horners. Fuses: P chunk reduction * 1/p!;
// silu(x+att) -> h; h -> Hf bf16 hi/lo fragment stores.
__global__ __launch_bounds__(256)
void attn_eval(const float* __restrict__ q, const float* __restrict__ P,
               const float* __restrict__ x, float* __restrict__ h,
               short* __restrict__ Hf)
{
  const int b = blockIdx.x;
  const int i = blockIdx.y * 256 + threadIdx.x;
  __shared__ float cm[NMOM];
  for (int e = threadIdx.x; e < NMOM; e += 256) {
    float s = 0.f;
    #pragma unroll
    for (int c = 0; c < NCHUNK; ++c) s += P[((size_t)b * NCHUNK + c) * NMOM + e];
    int p = e % (2 * NP); if (p >= NP) p -= NP;
    cm[e] = s * c_invfact[p];
  }
  __syncthreads();
  size_t o = (size_t)b * N + i;
  float qv = q[o];
  float qc = fminf(fmaxf(qv, QLO + 0.01f), -QLO - 0.01f);  // 7.8-sigma guard
  int m = (int)((qc - QLO) * QINVBW);
  float gam = QLO + ((float)m + 0.5f) * QBW;
  float d = qv - gam;
  const float* Sp = &cm[m * 18];
  float f = Sp[NP - 1], g = Sp[2 * NP - 1];
  #pragma unroll
  for (int p = NP - 2; p >= 0; --p) {
    f = fmaf(f, d, Sp[p]);
    g = fmaf(g, d, Sp[NP + p]);
  }
  float att = g / f;
  float z = x[o] + att;
  float hv = z / (1.f + fast_exp2(-1.44269504f * z));
  h[o] = hv;
  unsigned short hi = f2bf_rne(hv);
  unsigned short lo = f2bf_rne(hv - bf2f(hi));
  size_t base = (size_t)(b >> 4) * 65536 + (size_t)(i >> 5) * 512
              + (size_t)((b & 15) | (((i >> 3) & 3) << 4)) * 8 + (size_t)(i & 7);
  Hf[base] = (short)hi;
  Hf[base + 131072] = (short)lo;
}

// out = silu(h + (GP0+GP1) + bp)
__global__ __launch_bounds__(256)
void finalize_kernel(const float* __restrict__ h, const float* __restrict__ GP,
                     const float* __restrict__ bp, float* __restrict__ out)
{
  int idx = (blockIdx.x * 256 + threadIdx.x) * 4;
  int i = idx & (N - 1);
  const float* T0 = GP;
  const float* T1 = GP + (size_t)1 * BATCH * N;
  float4 hv = *(const float4*)&h[idx];
  float4 a  = *(const float4*)&T0[idx];
  float4 bt = *(const float4*)&T1[idx];
  float4 bb = *(const float4*)&bp[i];
  float4 z, o;
  z.x = hv.x + (a.x + bt.x) + bb.x;
  z.y = hv.y + (a.y + bt.y) + bb.y;
  z.z = hv.z + (a.z + bt.z) + bb.z;
  z.w = hv.w + (a.w + bt.w) + bb.w;
  o.x = z.x / (1.f + fast_exp2(-1.44269504f * z.x));
  o.y = z.y / (1.f + fast_exp2(-1.44269504f * z.y));
  o.z = z.z / (1.f + fast_exp2(-1.44269504f * z.z));
  o.w = z.w / (1.f + fast_exp2(-1.44269504f * z.w));
  *(float4*)&out[idx] = o;
}

extern "C" void kernel_launch(void* const* d_in, const int* in_sizes, int n_in,
                              void* d_out, int out_size, void* d_ws, size_t ws_size,
                              hipStream_t stream)
{
  const float* x  = (const float*)d_in[0];
  const float* Wq = (const float*)d_in[1];
  const float* bq = (const float*)d_in[2];
  const float* Wk = (const float*)d_in[3];
  const float* bk = (const float*)d_in[4];
  const float* Wv = (const float*)d_in[5];
  const float* bv = (const float*)d_in[6];
  const float* Wp = (const float*)d_in[7];
  const float* bp = (const float*)d_in[8];
  float* out = (float*)d_out;

  float* GP = (float*)d_ws;                        // 2 x [32][4096] gemm_p partials
  float* q  = GP + (size_t)2 * BATCH * N;
  float* kk = q  + BATCH * N;
  float* vv = kk + BATCH * N;
  float* h  = vv + BATCH * N;
  short* Xf = (short*)(h + BATCH * N);             // 512 KB frag arrays (x)
  short* Hf = Xf + 262144;                         // 512 KB frag arrays (h)
  float* P  = (float*)(Hf + 262144);               // [32][8][1152] moment partials

  prep_frags<<<dim3(128), 256, 0, stream>>>(x, Xf);
  gemm3<<<dim3(256, 3), 512, 0, stream>>>(Xf, Wq, bq, q, Wk, bk, kk, Wv, bv, vv);
  moments_a<<<dim3(BATCH, NCHUNK), 1024, 0, stream>>>(kk, vv, P);
  attn_eval<<<dim3(BATCH, 16), 256, 0, stream>>>(q, P, x, h, Hf);
  gemm_p<<<dim3(256, 2), 512, 0, stream>>>(Hf, Wp, GP);
  finalize_kernel<<<dim3(128), 256, 0, stream>>>(h, GP, bp, out);
}